// Round 6
// baseline (736549.805 us; speedup 1.0000x reference)
//
#include <hip/hip_runtime.h>

#define NT 256
#define NB 1024
#define TILE 64

// d_ws layout:
//   f32 chains[8]  at byte 0    : s-chains bins0..3, sq-chains bins0..3 (seq kernel writes)
//   f64 diag[6]    at byte 128  : ad, dd, c0, c1, c2, c3 (atomic-accumulated)

__global__ __launch_bounds__(64) void zero_diag(double* __restrict__ diag) {
    if (threadIdx.x < 6) diag[threadIdx.x] = 0.0;
}

// ---- parallel diagnostics (mean(|d|), mean(d^2)) + exact true counts ----
__global__ __launch_bounds__(NT) void diag_kernel(
    const float* __restrict__ w, const float* __restrict__ alpha,
    double* __restrict__ diag, int n4, long long n)
{
    const float a = alpha[0];
    float ad = 0.f, dd = 0.f;
    int c0 = 0, c1 = 0, c2 = 0, c3 = 0;

    auto pe = [&](float x) {
        float r  = __fdiv_rn(x, a);                 // IEEE divide, matches np w/a
        float cl = fminf(1.0f, fmaxf(-2.0f, r));
        float bf = rintf(cl);                       // half-to-even = np.round
        int   k  = (int)bf;
        float wq = __fmul_rn(bf, a);                // np: bins*a (separate round)
        float d  = __fsub_rn(x, wq);                // np: w - wq (no fma)
        ad = __fadd_rn(ad, fabsf(d));
        dd = __fadd_rn(dd, __fmul_rn(d, d));
        if      (k == -2) c0++;
        else if (k == -1) c1++;
        else if (k ==  0) c2++;
        else              c3++;
    };

    const float4* __restrict__ w4 = reinterpret_cast<const float4*>(w);
    const int stride = gridDim.x * NT;
    for (int i = blockIdx.x * NT + threadIdx.x; i < n4; i += stride) {
        float4 v = w4[i];
        pe(v.x); pe(v.y); pe(v.z); pe(v.w);
    }
    if (blockIdx.x == 0 && threadIdx.x == 0) {
        for (long long i = (long long)n4 * 4; i < n; ++i) pe(w[i]);
    }

    double vals[6] = { (double)ad, (double)dd,
                       (double)c0, (double)c1, (double)c2, (double)c3 };

    __shared__ double red[NT];
    const int tid = threadIdx.x;
#pragma unroll
    for (int j = 0; j < 6; ++j) {
        red[tid] = vals[j];
        __syncthreads();
        for (int s = NT / 2; s > 0; s >>= 1) {
            if (tid < s) red[tid] += red[tid + s];
            __syncthreads();
        }
        if (tid == 0) atomicAdd(&diag[j], red[0]);
        __syncthreads();
    }
}

// ---- exact sequential-f32 emulation of np.add.at segment sums ----
// One wave. Lanes 0-7 own chains (rows 0-3: s for bins 0-3, rows 4-7: sq).
// Adding literal +0.0f is an exact no-op in IEEE RN, so unconditional
// ordered adds over the masked tile reproduce the sequential scatter-add
// bit-for-bit in array order.
__global__ __launch_bounds__(64) void seq_chains(
    const float* __restrict__ w, const float* __restrict__ alpha,
    float* __restrict__ chains, long long n)
{
    const float a = alpha[0];
    const int lane = threadIdx.x;
    const int myrow = lane & 7;
    __shared__ float val[8][TILE];

    float acc = 0.0f;
    const long long ntiles = (n + TILE - 1) / TILE;

    // prefetch tile 0
    float x_next = (lane < n) ? w[lane] : 0.0f;

    for (long long t = 0; t < ntiles; ++t) {
        float x = x_next;
        // prefetch next tile (hidden under this tile's serial adds)
        {
            long long idxn = (t + 1) * TILE + lane;
            x_next = (idxn < n) ? w[idxn] : 0.0f;
        }
        const long long idx = t * TILE + lane;
        const bool valid = (idx < n);

        float r  = __fdiv_rn(x, a);
        float cl = fminf(1.0f, fmaxf(-2.0f, r));
        int   k  = (int)rintf(cl);          // -2..1
        int   row = k + 2;                  // 0..3
        float xx = __fmul_rn(x, x);         // np computes w*w in f32 first

#pragma unroll
        for (int b = 0; b < 4; ++b) {
            val[b][lane]     = (valid && row == b) ? x  : 0.0f;
            val[4 + b][lane] = (valid && row == b) ? xx : 0.0f;
        }
        __syncthreads();

        if (lane < 8) {
#pragma unroll
            for (int e4 = 0; e4 < TILE / 4; ++e4) {
                float4 v = *reinterpret_cast<const float4*>(&val[myrow][e4 * 4]);
                acc = __fadd_rn(acc, v.x);
                acc = __fadd_rn(acc, v.y);
                acc = __fadd_rn(acc, v.z);
                acc = __fadd_rn(acc, v.w);
            }
        }
        __syncthreads();
    }
    if (lane < 8) chains[lane] = acc;
}

// ---- finalize: faithful f32 post-processing of the saturated sums ----
__global__ void bin_finalize(const float* __restrict__ chains,
                             const double* __restrict__ diag,
                             const float* __restrict__ alpha,
                             float* __restrict__ out, long long n)
{
    const float a = alpha[0];
    const double cnt_true[4] = { diag[2], diag[3], diag[4], diag[5] };

    float tmse = 0.0f, tvar = 0.0f;
#pragma unroll
    for (int b = 0; b < 4; ++b) {
        // sequential-f32 count saturates exactly at 2^24 (ties-to-even)
        float cnt = (float)cnt_true[b];
        cnt = fminf(cnt, 16777216.0f);
        float safe = fmaxf(cnt, 1.0f);
        float s_np  = chains[b];
        float sq_np = chains[4 + b];
        float mean = __fdiv_rn(s_np, safe);
        float var  = __fsub_rn(__fdiv_rn(sq_np, safe), __fmul_rn(mean, mean));
        float lvl  = __fmul_rn((float)(b - 2), a);
        float e    = __fsub_rn(mean, lvl);
        if (cnt > 0.0f)  tmse = __fadd_rn(tmse, __fmul_rn(e, e));
        if (cnt >= 2.0f) tvar = __fadd_rn(tvar, var);
    }
    float loss = __fadd_rn(tmse, tvar);

    const double dn = (double)n;
    out[0] = loss;
    out[1] = tmse;
    out[2] = tvar;
    out[3] = (float)(diag[1] / dn);   // quantization_mse = mean(d*d)
    out[4] = (float)(diag[0] / dn);   // mean_distance   = mean(|d|)
}

extern "C" void kernel_launch(void* const* d_in, const int* in_sizes, int n_in,
                              void* d_out, int out_size, void* d_ws, size_t ws_size,
                              hipStream_t stream) {
    const float* w     = (const float*)d_in[0];
    const float* alpha = (const float*)d_in[1];
    float* out = (float*)d_out;
    long long n = (long long)in_sizes[0];
    int n4 = (int)(n >> 2);

    float*  chains = (float*)d_ws;
    double* diag   = (double*)((char*)d_ws + 128);

    zero_diag<<<1, 64, 0, stream>>>(diag);
    diag_kernel<<<NB, NT, 0, stream>>>(w, alpha, diag, n4, n);
    seq_chains<<<1, 64, 0, stream>>>(w, alpha, chains, n);
    bin_finalize<<<1, 1, 0, stream>>>(chains, diag, alpha, out, n);
}

// Round 7
// 2677.573 us; speedup vs baseline: 275.0811x; 275.0811x over previous
//
#include <hip/hip_runtime.h>
#include <cstdint>

#define TS 16384           // elements per tile
#define NE 24              // binade slots per chain
#define NCH 7

// chains: 0:s(-2) 1:s(-1) 2:s(+1) 3:q(-2) 4:q(-1) 5:q(0) 6:q(+1)
// (s(0) is a non-stalling random walk -> f64 in diag; counts -> min(true,2^24))
constexpr int H_CBIN[NCH] = {-2,-1, 1,-2,-1, 0, 1};
constexpr int H_CISQ[NCH] = { 0, 0, 0, 1, 1, 1, 1};
constexpr int H_CE0 [NCH] = { 2, 2, 2, 0, 0, 0, 0};

constexpr float p2f(int k) {
    return k >= 0 ? (float)(1ULL << k) : 1.0f / (float)(1ULL << (-k));
}

__device__ __forceinline__ int binof(float x, float a) {
    float r  = __fdiv_rn(x, a);
    float cl = fminf(1.0f, fmaxf(-2.0f, r));
    return (int)rintf(cl);             // round-half-even = np.round
}

__device__ __forceinline__ double wred64(double v) {
#pragma unroll
    for (int d = 32; d >= 1; d >>= 1) v += __shfl_xor(v, d, 64);
    return v;
}

// ---------------- diagnostics: ad, dd, counts, s0 (f64/exact) ----------------
__global__ __launch_bounds__(64) void zero_fast(double* __restrict__ diag,
                                                float* __restrict__ chains) {
    if (threadIdx.x < 8) diag[threadIdx.x] = 0.0;
    if (threadIdx.x < 8) chains[threadIdx.x] = 0.0f;
}

__global__ __launch_bounds__(256) void diag7(const float* __restrict__ w,
        const float* __restrict__ alpha, double* __restrict__ diag, long long n)
{
    const float a = alpha[0];
    double ad = 0.0, dd = 0.0, s0 = 0.0;
    int c0 = 0, c1 = 0, c2 = 0, c3 = 0;

    auto pe = [&](float x) {
        float r  = __fdiv_rn(x, a);
        float cl = fminf(1.0f, fmaxf(-2.0f, r));
        float bf = rintf(cl);
        int   k  = (int)bf;
        float wq = __fmul_rn(bf, a);
        float d  = __fsub_rn(x, wq);
        ad += (double)fabsf(d);
        dd += (double)__fmul_rn(d, d);
        if (k == 0) s0 += (double)x;
        if      (k == -2) c0++;
        else if (k == -1) c1++;
        else if (k ==  0) c2++;
        else              c3++;
    };

    const long long n4 = n >> 2;
    const float4* __restrict__ w4 = reinterpret_cast<const float4*>(w);
    const long long stride = (long long)gridDim.x * 256;
    for (long long i = (long long)blockIdx.x * 256 + threadIdx.x; i < n4; i += stride) {
        float4 v = w4[i];
        pe(v.x); pe(v.y); pe(v.z); pe(v.w);
    }
    if (blockIdx.x == 0 && threadIdx.x == 0)
        for (long long i = n4 << 2; i < n; ++i) pe(w[i]);

    double vals[7] = {ad, dd, (double)c0, (double)c1, (double)c2, (double)c3, s0};
    __shared__ double red[256];
    const int tid = threadIdx.x;
#pragma unroll
    for (int j = 0; j < 7; ++j) {
        red[tid] = vals[j];
        __syncthreads();
        for (int s = 128; s > 0; s >>= 1) {
            if (tid < s) red[tid] += red[tid + s];
            __syncthreads();
        }
        if (tid == 0) atomicAdd(&diag[j], red[0]);
        __syncthreads();
    }
}

// ---------------- pass A: per-tile K sums for 24 binade slots ----------------
template<int CA, int CB>
__device__ __forceinline__ void passA_body(const float* __restrict__ w, float a,
        double* __restrict__ Ktab, long long n, long long ntiles)
{
    constexpr int BA  = H_CBIN[CA];
    constexpr int QA  = H_CISQ[CA];
    constexpr int E0A = H_CE0[CA];
    constexpr int BB  = (CB >= 0) ? H_CBIN[CB] : 99;
    constexpr int QB  = (CB >= 0) ? H_CISQ[CB] : 0;
    constexpr int E0B = (CB >= 0) ? H_CE0[CB] : 0;

    const long long tile = blockIdx.x;
    const int tid = threadIdx.x;
    int accA[NE], accB[NE];
#pragma unroll
    for (int s = 0; s < NE; ++s) { accA[s] = 0; accB[s] = 0; }

    const long long base4 = tile * (TS / 4);
#pragma unroll 1
    for (int i = 0; i < TS / (4 * 256); ++i) {
        const long long fi4 = base4 + (long long)i * 256 + tid;
        const long long fe  = fi4 * 4;
        float4 v = make_float4(0.f, 0.f, 0.f, 0.f);
        if (fe + 3 < n) v = *reinterpret_cast<const float4*>(w + fe);
        else if (fe < n) {
            v.x = w[fe];
            if (fe + 1 < n) v.y = w[fe + 1];
            if (fe + 2 < n) v.z = w[fe + 2];
        }
        const float e4[4] = {v.x, v.y, v.z, v.w};
#pragma unroll
        for (int j = 0; j < 4; ++j) {
            const float x = e4[j];
            const int b = binof(x, a);
            if (b == BA) {
                const float xv = QA ? __fmul_rn(x, x) : fabsf(x);
#pragma unroll
                for (int s = 0; s < NE; ++s)
                    accA[s] += (int)rintf(xv * p2f(23 - E0A - s));
            } else if (CB >= 0 && b == BB) {
                const float xv = QB ? __fmul_rn(x, x) : fabsf(x);
#pragma unroll
                for (int s = 0; s < NE; ++s)
                    accB[s] += (int)rintf(xv * p2f(23 - E0B - s));
            }
        }
    }

    __shared__ double lred[4][2 * NE];
    const int lane = tid & 63, wid = tid >> 6;
#pragma unroll
    for (int s = 0; s < NE; ++s) {
        double va = wred64((double)accA[s]);
        double vb = wred64((double)accB[s]);
        if (lane == 0) { lred[wid][s] = va; lred[wid][NE + s] = vb; }
    }
    __syncthreads();
    if (tid < 2 * NE) {
        const double sum = lred[0][tid] + lred[1][tid] + lred[2][tid] + lred[3][tid];
        const int c = (tid < NE) ? CA : CB;
        const int s = (tid < NE) ? tid : tid - NE;
        if (c >= 0)
            Ktab[((long long)(c * NE + s)) * ntiles + tile] = sum;
    }
}

__global__ __launch_bounds__(256) void passA_kernel(const float* __restrict__ w,
        const float* __restrict__ alpha, double* __restrict__ Ktab,
        long long n, long long ntiles)
{
    const float a = alpha[0];
    switch (blockIdx.y) {
        case 0:  passA_body<0, 1>(w, a, Ktab, n, ntiles); break;
        case 1:  passA_body<2, 3>(w, a, Ktab, n, ntiles); break;
        case 2:  passA_body<4, 5>(w, a, Ktab, n, ntiles); break;
        default: passA_body<6,-1>(w, a, Ktab, n, ntiles); break;
    }
}

// -------- exact span walker: 1024-elem steps, 64-lane prefix, true-add fixes --------
__device__ void walk_span(const float* __restrict__ w, long long n, float a,
                          int mybin, int myisq, double& A,
                          long long lo, long long hi, int lane)
{
    for (long long base = lo; base < hi; base += 1024) {
        float xs[16];
        const long long e0 = base + (long long)lane * 16;
#pragma unroll
        for (int q4 = 0; q4 < 4; ++q4) {
            const long long fi = e0 + q4 * 4;
            float4 v = make_float4(0.f, 0.f, 0.f, 0.f);
            if (fi + 3 < n) v = *reinterpret_cast<const float4*>(w + fi);
            else {
                if (fi     < n) v.x = w[fi];
                if (fi + 1 < n) v.y = w[fi + 1];
                if (fi + 2 < n) v.z = w[fi + 2];
            }
            const float e4[4] = {v.x, v.y, v.z, v.w};
#pragma unroll
            for (int j = 0; j < 4; ++j) {
                const float x = e4[j];
                float xv = 0.0f;
                if (binof(x, a) == mybin) xv = myisq ? __fmul_rn(x, x) : fabsf(x);
                xs[q4 * 4 + j] = xv;
            }
        }

        int C = 0;
        while (C < 64) {
            if (A > 0.0) {
                const int e = ilogb(A);
                const double u  = ldexp(1.0, e - 23);
                const double Bb = ldexp(1.0, e + 1);
                const double sc = ldexp(1.0, 23 - e);
                double kd = 0.0;
                if (lane >= C) {
#pragma unroll
                    for (int j = 0; j < 16; ++j) kd += rint((double)xs[j] * sc);
                }
                const bool big = kd >= 1099511627776.0;   // 2^40: force serial path
                double p = kd;
#pragma unroll
                for (int d = 1; d < 64; d <<= 1) {
                    double tt = __shfl_up(p, d, 64);
                    if (lane >= d) p += tt;
                }
                const bool cross = (lane >= C) && (big || (A + u * p >= Bb));
                const unsigned long long bal = __ballot(cross);
                if (bal == 0ULL) {                        // whole remainder in-binade: exact
                    const double tot = __shfl(p, 63);
                    A = A + u * tot;
                    break;
                }
                const int F = __ffsll((long long)bal) - 1;
                double An = 0.0;
                if (lane == F) {
                    const double Aex = A + u * (p - kd);  // exact state before lane F
                    float Af = (float)Aex;
#pragma unroll
                    for (int j = 0; j < 16; ++j) Af = __fadd_rn(Af, xs[j]);
                    An = (double)Af;
                }
                A = __shfl(An, F);
                C = F + 1;
            } else {                                      // A == 0: find first live lane
                bool has = false;
                if (lane >= C) {
#pragma unroll
                    for (int j = 0; j < 16; ++j) has = has || (xs[j] > 0.0f);
                }
                const unsigned long long bal = __ballot(has);
                if (bal == 0ULL) break;
                const int F = __ffsll((long long)bal) - 1;
                double An = 0.0;
                if (lane == F) {
                    float Af = 0.0f;
#pragma unroll
                    for (int j = 0; j < 16; ++j) Af = __fadd_rn(Af, xs[j]);
                    An = (double)Af;
                }
                A = __shfl(An, F);
                C = F + 1;
            }
        }
    }
}

// ---------------- pass B: per-chain binade walk over tiles ----------------
__global__ __launch_bounds__(512) void walk_kernel(const float* __restrict__ w,
        const float* __restrict__ alpha, const double* __restrict__ Ktab,
        float* __restrict__ chains, long long n, long long ntiles)
{
    const int wave = threadIdx.x >> 6;
    const int lane = threadIdx.x & 63;
    if (wave >= NCH) return;
    const int ch = wave;
    const int CBIN[NCH] = {-2,-1, 1,-2,-1, 0, 1};
    const int CISQ[NCH] = { 0, 0, 0, 1, 1, 1, 1};
    const int CE0 [NCH] = { 2, 2, 2, 0, 0, 0, 0};
    const int OSLOT[NCH]= { 0, 1, 3, 4, 5, 6, 7};
    const int mybin = CBIN[ch], myisq = CISQ[ch], E0 = CE0[ch];
    const float a = alpha[0];

    double A = 0.0;
    walk_span(w, n, a, mybin, myisq, A, 0LL, (TS < n ? (long long)TS : n), lane);

    long long t = 1;
    int curslot = -1; long long wbase = -1000; double Kw = 0.0;
    while (t < ntiles) {
        const long long lo = t * (long long)TS;
        const long long hi = (lo + TS < n) ? lo + TS : n;
        bool consumed = false;
        if (A > 0.0) {
            const int e = ilogb(A);
            const int slot = e - E0;
            if (slot >= 0 && slot < NE) {
                if (slot != curslot || t < wbase || t >= wbase + 64) {
                    curslot = slot; wbase = t;
                    const long long wt = wbase + lane;
                    Kw = (wt < ntiles)
                       ? Ktab[((long long)(ch * NE + slot)) * ntiles + wt] : 0.0;
                }
                const double K  = __shfl(Kw, (int)(t - wbase), 64);
                const double u  = ldexp(1.0, e - 23);
                const double Bb = ldexp(1.0, e + 1);
                const double An = A + u * K;
                if (An <= Bb) { A = An; consumed = true; }   // monotone => exact
            }
        }
        if (!consumed) walk_span(w, n, a, mybin, myisq, A, lo, hi, lane);
        ++t;
    }
    if (lane == 0) chains[OSLOT[ch]] = (float)A;
}

// ---------------- finalize: validated R6 f32 emulation ----------------
__global__ void fin_fast(const float* __restrict__ chains,
                         const double* __restrict__ diag,
                         const float* __restrict__ alpha,
                         float* __restrict__ out, long long n)
{
    const float a = alpha[0];
    const float s_np[4]  = { -chains[0], -chains[1], (float)diag[6], chains[3] };
    const float sq_np[4] = {  chains[4],  chains[5],  chains[6],     chains[7] };
    float tmse = 0.f, tvar = 0.f;
#pragma unroll
    for (int b = 0; b < 4; ++b) {
        float cnt = fminf((float)diag[2 + b], 16777216.0f);   // exact f32-chain saturation
        float safe = fmaxf(cnt, 1.0f);
        float mean = __fdiv_rn(s_np[b], safe);
        float var  = __fsub_rn(__fdiv_rn(sq_np[b], safe), __fmul_rn(mean, mean));
        float lvl  = __fmul_rn((float)(b - 2), a);
        float e    = __fsub_rn(mean, lvl);
        if (cnt > 0.f)  tmse = __fadd_rn(tmse, __fmul_rn(e, e));
        if (cnt >= 2.f) tvar = __fadd_rn(tvar, var);
    }
    out[0] = __fadd_rn(tmse, tvar);
    out[1] = tmse;
    out[2] = tvar;
    out[3] = (float)(diag[1] / (double)n);
    out[4] = (float)(diag[0] / (double)n);
}

// ================= R6 fallback (bit-exact serial, if ws too small) =================
__global__ __launch_bounds__(64) void zero_diag6(double* __restrict__ diag) {
    if (threadIdx.x < 6) diag[threadIdx.x] = 0.0;
}
__global__ __launch_bounds__(256) void diag6(const float* __restrict__ w,
        const float* __restrict__ alpha, double* __restrict__ diag, int n4, long long n)
{
    const float a = alpha[0];
    float ad = 0.f, dd = 0.f; int c0=0,c1=0,c2=0,c3=0;
    auto pe = [&](float x) {
        float r = __fdiv_rn(x, a);
        float cl = fminf(1.0f, fmaxf(-2.0f, r));
        float bf = rintf(cl); int k = (int)bf;
        float wq = __fmul_rn(bf, a); float d = __fsub_rn(x, wq);
        ad = __fadd_rn(ad, fabsf(d)); dd = __fadd_rn(dd, __fmul_rn(d, d));
        if (k==-2) c0++; else if (k==-1) c1++; else if (k==0) c2++; else c3++;
    };
    const float4* w4 = reinterpret_cast<const float4*>(w);
    const int stride = gridDim.x * 256;
    for (int i = blockIdx.x * 256 + threadIdx.x; i < n4; i += stride) {
        float4 v = w4[i]; pe(v.x); pe(v.y); pe(v.z); pe(v.w);
    }
    if (blockIdx.x == 0 && threadIdx.x == 0)
        for (long long i = (long long)n4 * 4; i < n; ++i) pe(w[i]);
    double vals[6] = {(double)ad,(double)dd,(double)c0,(double)c1,(double)c2,(double)c3};
    __shared__ double red[256];
    const int tid = threadIdx.x;
#pragma unroll
    for (int j = 0; j < 6; ++j) {
        red[tid] = vals[j]; __syncthreads();
        for (int s = 128; s > 0; s >>= 1) { if (tid < s) red[tid] += red[tid+s]; __syncthreads(); }
        if (tid == 0) atomicAdd(&diag[j], red[0]);
        __syncthreads();
    }
}
__global__ __launch_bounds__(64) void seq_chains(const float* __restrict__ w,
        const float* __restrict__ alpha, float* __restrict__ chains, long long n)
{
    const float a = alpha[0];
    const int lane = threadIdx.x; const int myrow = lane & 7;
    __shared__ float val[8][64];
    float acc = 0.0f;
    const long long ntl = (n + 63) / 64;
    float x_next = (lane < n) ? w[lane] : 0.0f;
    for (long long t = 0; t < ntl; ++t) {
        float x = x_next;
        { long long idxn = (t + 1) * 64 + lane; x_next = (idxn < n) ? w[idxn] : 0.0f; }
        const long long idx = t * 64 + lane;
        const bool valid = (idx < n);
        float r = __fdiv_rn(x, a);
        float cl = fminf(1.0f, fmaxf(-2.0f, r));
        int k = (int)rintf(cl); int row = k + 2;
        float xx = __fmul_rn(x, x);
#pragma unroll
        for (int b = 0; b < 4; ++b) {
            val[b][lane]     = (valid && row == b) ? x  : 0.0f;
            val[4 + b][lane] = (valid && row == b) ? xx : 0.0f;
        }
        __syncthreads();
        if (lane < 8) {
#pragma unroll
            for (int e4i = 0; e4i < 16; ++e4i) {
                float4 v = *reinterpret_cast<const float4*>(&val[myrow][e4i * 4]);
                acc = __fadd_rn(acc, v.x); acc = __fadd_rn(acc, v.y);
                acc = __fadd_rn(acc, v.z); acc = __fadd_rn(acc, v.w);
            }
        }
        __syncthreads();
    }
    if (lane < 8) chains[lane] = acc;
}
__global__ void fin_seq(const float* __restrict__ chains, const double* __restrict__ diag,
                        const float* __restrict__ alpha, float* __restrict__ out, long long n)
{
    const float a = alpha[0];
    float tmse = 0.0f, tvar = 0.0f;
#pragma unroll
    for (int b = 0; b < 4; ++b) {
        float cnt = fminf((float)diag[2 + b], 16777216.0f);
        float safe = fmaxf(cnt, 1.0f);
        float mean = __fdiv_rn(chains[b], safe);
        float var  = __fsub_rn(__fdiv_rn(chains[4 + b], safe), __fmul_rn(mean, mean));
        float lvl  = __fmul_rn((float)(b - 2), a);
        float e    = __fsub_rn(mean, lvl);
        if (cnt > 0.0f)  tmse = __fadd_rn(tmse, __fmul_rn(e, e));
        if (cnt >= 2.0f) tvar = __fadd_rn(tvar, var);
    }
    out[0] = __fadd_rn(tmse, tvar);
    out[1] = tmse; out[2] = tvar;
    out[3] = (float)(diag[1] / (double)n);
    out[4] = (float)(diag[0] / (double)n);
}

// ---------------- launcher ----------------
extern "C" void kernel_launch(void* const* d_in, const int* in_sizes, int n_in,
                              void* d_out, int out_size, void* d_ws, size_t ws_size,
                              hipStream_t stream) {
    const float* w     = (const float*)d_in[0];
    const float* alpha = (const float*)d_in[1];
    float* out = (float*)d_out;
    const long long n = (long long)in_sizes[0];
    const long long ntiles = (n + TS - 1) / TS;
    const size_t ktab_bytes = (size_t)NCH * NE * (size_t)ntiles * sizeof(double);
    const size_t need = ktab_bytes + 128;

    if (ws_size >= need) {
        double* Ktab   = (double*)d_ws;
        double* diag   = (double*)((char*)d_ws + ktab_bytes);        // 8 doubles
        float*  chains = (float*)((char*)d_ws + ktab_bytes + 64);    // 8 floats

        zero_fast<<<1, 64, 0, stream>>>(diag, chains);
        diag7<<<1024, 256, 0, stream>>>(w, alpha, diag, n);
        dim3 ga((unsigned)ntiles, 4);
        passA_kernel<<<ga, 256, 0, stream>>>(w, alpha, Ktab, n, ntiles);
        walk_kernel<<<1, 512, 0, stream>>>(w, alpha, Ktab, chains, n, ntiles);
        fin_fast<<<1, 1, 0, stream>>>(chains, diag, alpha, out, n);
    } else {
        float*  chains = (float*)d_ws;
        double* diag   = (double*)((char*)d_ws + 128);
        zero_diag6<<<1, 64, 0, stream>>>(diag);
        diag6<<<1024, 256, 0, stream>>>(w, alpha, diag, (int)(n >> 2), n);
        seq_chains<<<1, 64, 0, stream>>>(w, alpha, chains, n);
        fin_seq<<<1, 1, 0, stream>>>(chains, diag, alpha, out, n);
    }
}

// Round 8
// 1698.137 us; speedup vs baseline: 433.7399x; 1.5768x over previous
//
#include <hip/hip_runtime.h>
#include <cstdint>

#define TS 16384           // elements per tile
#define NE 24              // binade slots per chain
#define NCH 7

// chains: 0:s(-2) 1:s(-1) 2:s(+1) 3:q(-2) 4:q(-1) 5:q(0) 6:q(+1)
// (s(0) is a non-stalling random walk -> f64 in diag; counts -> min(true,2^24))
constexpr int H_CBIN[NCH] = {-2,-1, 1,-2,-1, 0, 1};
constexpr int H_CISQ[NCH] = { 0, 0, 0, 1, 1, 1, 1};
constexpr int H_CE0 [NCH] = { 2, 2, 2, 0, 0, 0, 0};

constexpr float p2f(int k) {
    return k >= 0 ? (float)(1ULL << k) : 1.0f / (float)(1ULL << (-k));
}

__device__ __forceinline__ int binof(float x, float a) {
    float r  = __fdiv_rn(x, a);
    float cl = fminf(1.0f, fmaxf(-2.0f, r));
    return (int)rintf(cl);             // round-half-even = np.round
}

__device__ __forceinline__ double wred64(double v) {
#pragma unroll
    for (int d = 32; d >= 1; d >>= 1) v += __shfl_xor(v, d, 64);
    return v;
}

// ---------------- diagnostics: ad, dd, counts, s0 (f64/exact) ----------------
__global__ __launch_bounds__(64) void zero_fast(double* __restrict__ diag,
                                                float* __restrict__ chains) {
    if (threadIdx.x < 8) diag[threadIdx.x] = 0.0;
    if (threadIdx.x < 8) chains[threadIdx.x] = 0.0f;
}

__global__ __launch_bounds__(256) void diag7(const float* __restrict__ w,
        const float* __restrict__ alpha, double* __restrict__ diag, long long n)
{
    const float a = alpha[0];
    double ad = 0.0, dd = 0.0, s0 = 0.0;
    int c0 = 0, c1 = 0, c2 = 0, c3 = 0;

    auto pe = [&](float x) {
        float r  = __fdiv_rn(x, a);
        float cl = fminf(1.0f, fmaxf(-2.0f, r));
        float bf = rintf(cl);
        int   k  = (int)bf;
        float wq = __fmul_rn(bf, a);
        float d  = __fsub_rn(x, wq);
        ad += (double)fabsf(d);
        dd += (double)__fmul_rn(d, d);
        if (k == 0) s0 += (double)x;
        if      (k == -2) c0++;
        else if (k == -1) c1++;
        else if (k ==  0) c2++;
        else              c3++;
    };

    const long long n4 = n >> 2;
    const float4* __restrict__ w4 = reinterpret_cast<const float4*>(w);
    const long long stride = (long long)gridDim.x * 256;
    for (long long i = (long long)blockIdx.x * 256 + threadIdx.x; i < n4; i += stride) {
        float4 v = w4[i];
        pe(v.x); pe(v.y); pe(v.z); pe(v.w);
    }
    if (blockIdx.x == 0 && threadIdx.x == 0)
        for (long long i = n4 << 2; i < n; ++i) pe(w[i]);

    double vals[7] = {ad, dd, (double)c0, (double)c1, (double)c2, (double)c3, s0};
    __shared__ double red[256];
    const int tid = threadIdx.x;
#pragma unroll
    for (int j = 0; j < 7; ++j) {
        red[tid] = vals[j];
        __syncthreads();
        for (int s = 128; s > 0; s >>= 1) {
            if (tid < s) red[tid] += red[tid + s];
            __syncthreads();
        }
        if (tid == 0) atomicAdd(&diag[j], red[0]);
        __syncthreads();
    }
}

// ---------------- pass A: per-tile K sums for 24 binade slots ----------------
template<int CA, int CB>
__device__ __forceinline__ void passA_body(const float* __restrict__ w, float a,
        double* __restrict__ Ktab, long long n, long long ntiles)
{
    constexpr int BA  = H_CBIN[CA];
    constexpr int QA  = H_CISQ[CA];
    constexpr int E0A = H_CE0[CA];
    constexpr int BB  = (CB >= 0) ? H_CBIN[CB] : 99;
    constexpr int QB  = (CB >= 0) ? H_CISQ[CB] : 0;
    constexpr int E0B = (CB >= 0) ? H_CE0[CB] : 0;

    const long long tile = blockIdx.x;
    const int tid = threadIdx.x;
    int accA[NE], accB[NE];
#pragma unroll
    for (int s = 0; s < NE; ++s) { accA[s] = 0; accB[s] = 0; }

    const long long base4 = tile * (TS / 4);
#pragma unroll 1
    for (int i = 0; i < TS / (4 * 256); ++i) {
        const long long fi4 = base4 + (long long)i * 256 + tid;
        const long long fe  = fi4 * 4;
        float4 v = make_float4(0.f, 0.f, 0.f, 0.f);
        if (fe + 3 < n) v = *reinterpret_cast<const float4*>(w + fe);
        else if (fe < n) {
            v.x = w[fe];
            if (fe + 1 < n) v.y = w[fe + 1];
            if (fe + 2 < n) v.z = w[fe + 2];
        }
        const float e4[4] = {v.x, v.y, v.z, v.w};
#pragma unroll
        for (int j = 0; j < 4; ++j) {
            const float x = e4[j];
            const int b = binof(x, a);
            if (b == BA) {
                const float xv = QA ? __fmul_rn(x, x) : fabsf(x);
#pragma unroll
                for (int s = 0; s < NE; ++s)
                    accA[s] += (int)rintf(xv * p2f(23 - E0A - s));
            } else if (CB >= 0 && b == BB) {
                const float xv = QB ? __fmul_rn(x, x) : fabsf(x);
#pragma unroll
                for (int s = 0; s < NE; ++s)
                    accB[s] += (int)rintf(xv * p2f(23 - E0B - s));
            }
        }
    }

    __shared__ double lred[4][2 * NE];
    const int lane = tid & 63, wid = tid >> 6;
#pragma unroll
    for (int s = 0; s < NE; ++s) {
        double va = wred64((double)accA[s]);
        double vb = wred64((double)accB[s]);
        if (lane == 0) { lred[wid][s] = va; lred[wid][NE + s] = vb; }
    }
    __syncthreads();
    if (tid < 2 * NE) {
        const double sum = lred[0][tid] + lred[1][tid] + lred[2][tid] + lred[3][tid];
        const int c = (tid < NE) ? CA : CB;
        const int s = (tid < NE) ? tid : tid - NE;
        if (c >= 0)
            Ktab[((long long)(c * NE + s)) * ntiles + tile] = sum;
    }
}

__global__ __launch_bounds__(256) void passA_kernel(const float* __restrict__ w,
        const float* __restrict__ alpha, double* __restrict__ Ktab,
        long long n, long long ntiles)
{
    const float a = alpha[0];
    switch (blockIdx.y) {
        case 0:  passA_body<0, 1>(w, a, Ktab, n, ntiles); break;
        case 1:  passA_body<2, 3>(w, a, Ktab, n, ntiles); break;
        case 2:  passA_body<4, 5>(w, a, Ktab, n, ntiles); break;
        default: passA_body<6,-1>(w, a, Ktab, n, ntiles); break;
    }
}

// -------- exact span walker v2: 64 contiguous elems/lane, 4096-elem chunks --------
__device__ void walk_span2(const float* __restrict__ w, long long n, float a,
                           int mybin, int myisq, double& A,
                           long long lo, long long hi, int lane)
{
    for (long long base = lo; base < hi; base += 4096) {
        float xs[64];
        const long long e0 = base + (long long)lane * 64;
#pragma unroll
        for (int q4 = 0; q4 < 16; ++q4) {
            const long long fi = e0 + q4 * 4;
            float4 v = make_float4(0.f, 0.f, 0.f, 0.f);
            if (fi + 3 < n) v = *reinterpret_cast<const float4*>(w + fi);
            else {
                if (fi     < n) v.x = w[fi];
                if (fi + 1 < n) v.y = w[fi + 1];
                if (fi + 2 < n) v.z = w[fi + 2];
            }
            xs[q4 * 4 + 0] = v.x; xs[q4 * 4 + 1] = v.y;
            xs[q4 * 4 + 2] = v.z; xs[q4 * 4 + 3] = v.w;
        }
#pragma unroll
        for (int j = 0; j < 64; ++j) {
            const float x = xs[j];
            float xv = 0.0f;
            if (binof(x, a) == mybin) xv = myisq ? __fmul_rn(x, x) : fabsf(x);
            xs[j] = xv;
        }

        int C = 0;
        while (C < 64) {
            if (A > 0.0) {
                const int e = ilogb(A);
                const double u  = ldexp(1.0, e - 23);
                const double Bb = ldexp(1.0, e + 1);
                const double sc = ldexp(1.0, 23 - e);
                double kd = 0.0;
                if (lane >= C) {
#pragma unroll
                    for (int j = 0; j < 64; ++j) kd += rint((double)xs[j] * sc);
                }
                const bool big = kd >= 1099511627776.0;   // 2^40: force serial path
                double p = kd;
#pragma unroll
                for (int d = 1; d < 64; d <<= 1) {
                    double tt = __shfl_up(p, d, 64);
                    if (lane >= d) p += tt;
                }
                const bool cross = (lane >= C) && (big || (A + u * p >= Bb));
                const unsigned long long bal = __ballot(cross);
                if (bal == 0ULL) {                        // whole remainder in-binade: exact
                    const double tot = __shfl(p, 63);
                    A = A + u * tot;
                    break;
                }
                const int F = __ffsll((long long)bal) - 1;
                double An = 0.0;
                if (lane == F) {
                    const double Aex = A + u * (p - kd);  // exact state before lane F
                    float Af = (float)Aex;
#pragma unroll
                    for (int j = 0; j < 64; ++j) Af = __fadd_rn(Af, xs[j]);
                    An = (double)Af;
                }
                A = __shfl(An, F);
                C = F + 1;
            } else {                                      // A == 0: find first live lane
                bool has = false;
                if (lane >= C) {
#pragma unroll
                    for (int j = 0; j < 64; ++j) has = has || (xs[j] > 0.0f);
                }
                const unsigned long long bal = __ballot(has);
                if (bal == 0ULL) break;
                const int F = __ffsll((long long)bal) - 1;
                double An = 0.0;
                if (lane == F) {
                    float Af = 0.0f;
#pragma unroll
                    for (int j = 0; j < 64; ++j) Af = __fadd_rn(Af, xs[j]);
                    An = (double)Af;
                }
                A = __shfl(An, F);
                C = F + 1;
            }
        }
    }
}

// ---------------- pass B: windowed binade walk (64 tiles per step) ----------------
__global__ __launch_bounds__(512) void walk_kernel(const float* __restrict__ w,
        const float* __restrict__ alpha, const double* __restrict__ Ktab,
        float* __restrict__ chains, long long n, long long ntiles)
{
    const int wave = threadIdx.x >> 6;
    const int lane = threadIdx.x & 63;
    if (wave >= NCH) return;
    const int ch = wave;
    const int CBIN[NCH] = {-2,-1, 1,-2,-1, 0, 1};
    const int CISQ[NCH] = { 0, 0, 0, 1, 1, 1, 1};
    const int CE0 [NCH] = { 2, 2, 2, 0, 0, 0, 0};
    const int OSLOT[NCH]= { 0, 1, 3, 4, 5, 6, 7};
    const int mybin = CBIN[ch], myisq = CISQ[ch], E0 = CE0[ch];
    const float a = alpha[0];

    double A = 0.0;
    walk_span2(w, n, a, mybin, myisq, A, 0LL, (TS < n ? (long long)TS : n), lane);

    long long t = 1;
    while (t < ntiles) {
        if (A > 0.0) {
            const int e = ilogb(A);
            const int slot = e - E0;
            if (slot >= 0 && slot < NE) {
                // load a 64-tile K window for this slot, one tile per lane
                const long long wt = t + lane;
                double Kv = (wt < ntiles)
                          ? Ktab[((long long)(ch * NE + slot)) * ntiles + wt] : 0.0;
                double P = Kv;                       // inclusive prefix across lanes
#pragma unroll
                for (int d = 1; d < 64; d <<= 1) {
                    double tt = __shfl_up(P, d, 64);
                    if (lane >= d) P += tt;
                }
                const double u  = ldexp(1.0, e - 23);
                const double Bb = ldexp(1.0, e + 1);
                // bad: consuming through this lane's tile would leave the binade
                const bool bad = (A + u * P > Bb);
                const unsigned long long bal = __ballot(bad);
                if (bal == 0ULL) {                   // whole window consumable: exact
                    A += u * __shfl(P, 63);
                    t += 64;
                    continue;
                }
                const int F = __ffsll((long long)bal) - 1;
                if (F > 0) {                         // consume tiles t .. t+F-1 exactly
                    A += u * __shfl(P, F - 1);
                    t += F;
                }
                // tile t is the crossing tile: resolve exactly element-wise
                const long long lo = t * (long long)TS;
                const long long hi = (lo + TS < n) ? lo + TS : n;
                walk_span2(w, n, a, mybin, myisq, A, lo, hi, lane);
                ++t;
                continue;
            }
        }
        // A == 0 or binade below/above table range: exact serial tile
        const long long lo = t * (long long)TS;
        const long long hi = (lo + TS < n) ? lo + TS : n;
        walk_span2(w, n, a, mybin, myisq, A, lo, hi, lane);
        ++t;
    }
    if (lane == 0) chains[OSLOT[ch]] = (float)A;
}

// ---------------- finalize: validated R6 f32 emulation ----------------
__global__ void fin_fast(const float* __restrict__ chains,
                         const double* __restrict__ diag,
                         const float* __restrict__ alpha,
                         float* __restrict__ out, long long n)
{
    const float a = alpha[0];
    const float s_np[4]  = { -chains[0], -chains[1], (float)diag[6], chains[3] };
    const float sq_np[4] = {  chains[4],  chains[5],  chains[6],     chains[7] };
    float tmse = 0.f, tvar = 0.f;
#pragma unroll
    for (int b = 0; b < 4; ++b) {
        float cnt = fminf((float)diag[2 + b], 16777216.0f);   // exact f32-chain saturation
        float safe = fmaxf(cnt, 1.0f);
        float mean = __fdiv_rn(s_np[b], safe);
        float var  = __fsub_rn(__fdiv_rn(sq_np[b], safe), __fmul_rn(mean, mean));
        float lvl  = __fmul_rn((float)(b - 2), a);
        float e    = __fsub_rn(mean, lvl);
        if (cnt > 0.f)  tmse = __fadd_rn(tmse, __fmul_rn(e, e));
        if (cnt >= 2.f) tvar = __fadd_rn(tvar, var);
    }
    out[0] = __fadd_rn(tmse, tvar);
    out[1] = tmse;
    out[2] = tvar;
    out[3] = (float)(diag[1] / (double)n);
    out[4] = (float)(diag[0] / (double)n);
}

// ================= R6 fallback (bit-exact serial, if ws too small) =================
__global__ __launch_bounds__(64) void zero_diag6(double* __restrict__ diag) {
    if (threadIdx.x < 6) diag[threadIdx.x] = 0.0;
}
__global__ __launch_bounds__(256) void diag6(const float* __restrict__ w,
        const float* __restrict__ alpha, double* __restrict__ diag, int n4, long long n)
{
    const float a = alpha[0];
    float ad = 0.f, dd = 0.f; int c0=0,c1=0,c2=0,c3=0;
    auto pe = [&](float x) {
        float r = __fdiv_rn(x, a);
        float cl = fminf(1.0f, fmaxf(-2.0f, r));
        float bf = rintf(cl); int k = (int)bf;
        float wq = __fmul_rn(bf, a); float d = __fsub_rn(x, wq);
        ad = __fadd_rn(ad, fabsf(d)); dd = __fadd_rn(dd, __fmul_rn(d, d));
        if (k==-2) c0++; else if (k==-1) c1++; else if (k==0) c2++; else c3++;
    };
    const float4* w4 = reinterpret_cast<const float4*>(w);
    const int stride = gridDim.x * 256;
    for (int i = blockIdx.x * 256 + threadIdx.x; i < n4; i += stride) {
        float4 v = w4[i]; pe(v.x); pe(v.y); pe(v.z); pe(v.w);
    }
    if (blockIdx.x == 0 && threadIdx.x == 0)
        for (long long i = (long long)n4 * 4; i < n; ++i) pe(w[i]);
    double vals[6] = {(double)ad,(double)dd,(double)c0,(double)c1,(double)c2,(double)c3};
    __shared__ double red[256];
    const int tid = threadIdx.x;
#pragma unroll
    for (int j = 0; j < 6; ++j) {
        red[tid] = vals[j]; __syncthreads();
        for (int s = 128; s > 0; s >>= 1) { if (tid < s) red[tid] += red[tid+s]; __syncthreads(); }
        if (tid == 0) atomicAdd(&diag[j], red[0]);
        __syncthreads();
    }
}
__global__ __launch_bounds__(64) void seq_chains(const float* __restrict__ w,
        const float* __restrict__ alpha, float* __restrict__ chains, long long n)
{
    const float a = alpha[0];
    const int lane = threadIdx.x; const int myrow = lane & 7;
    __shared__ float val[8][64];
    float acc = 0.0f;
    const long long ntl = (n + 63) / 64;
    float x_next = (lane < n) ? w[lane] : 0.0f;
    for (long long t = 0; t < ntl; ++t) {
        float x = x_next;
        { long long idxn = (t + 1) * 64 + lane; x_next = (idxn < n) ? w[idxn] : 0.0f; }
        const long long idx = t * 64 + lane;
        const bool valid = (idx < n);
        float r = __fdiv_rn(x, a);
        float cl = fminf(1.0f, fmaxf(-2.0f, r));
        int k = (int)rintf(cl); int row = k + 2;
        float xx = __fmul_rn(x, x);
#pragma unroll
        for (int b = 0; b < 4; ++b) {
            val[b][lane]     = (valid && row == b) ? x  : 0.0f;
            val[4 + b][lane] = (valid && row == b) ? xx : 0.0f;
        }
        __syncthreads();
        if (lane < 8) {
#pragma unroll
            for (int e4i = 0; e4i < 16; ++e4i) {
                float4 v = *reinterpret_cast<const float4*>(&val[myrow][e4i * 4]);
                acc = __fadd_rn(acc, v.x); acc = __fadd_rn(acc, v.y);
                acc = __fadd_rn(acc, v.z); acc = __fadd_rn(acc, v.w);
            }
        }
        __syncthreads();
    }
    if (lane < 8) chains[lane] = acc;
}
__global__ void fin_seq(const float* __restrict__ chains, const double* __restrict__ diag,
                        const float* __restrict__ alpha, float* __restrict__ out, long long n)
{
    const float a = alpha[0];
    float tmse = 0.0f, tvar = 0.0f;
#pragma unroll
    for (int b = 0; b < 4; ++b) {
        float cnt = fminf((float)diag[2 + b], 16777216.0f);
        float safe = fmaxf(cnt, 1.0f);
        float mean = __fdiv_rn(chains[b], safe);
        float var  = __fsub_rn(__fdiv_rn(chains[4 + b], safe), __fmul_rn(mean, mean));
        float lvl  = __fmul_rn((float)(b - 2), a);
        float e    = __fsub_rn(mean, lvl);
        if (cnt > 0.0f)  tmse = __fadd_rn(tmse, __fmul_rn(e, e));
        if (cnt >= 2.0f) tvar = __fadd_rn(tvar, var);
    }
    out[0] = __fadd_rn(tmse, tvar);
    out[1] = tmse; out[2] = tvar;
    out[3] = (float)(diag[1] / (double)n);
    out[4] = (float)(diag[0] / (double)n);
}

// ---------------- launcher ----------------
extern "C" void kernel_launch(void* const* d_in, const int* in_sizes, int n_in,
                              void* d_out, int out_size, void* d_ws, size_t ws_size,
                              hipStream_t stream) {
    const float* w     = (const float*)d_in[0];
    const float* alpha = (const float*)d_in[1];
    float* out = (float*)d_out;
    const long long n = (long long)in_sizes[0];
    const long long ntiles = (n + TS - 1) / TS;
    const size_t ktab_bytes = (size_t)NCH * NE * (size_t)ntiles * sizeof(double);
    const size_t need = ktab_bytes + 128;

    if (ws_size >= need) {
        double* Ktab   = (double*)d_ws;
        double* diag   = (double*)((char*)d_ws + ktab_bytes);        // 8 doubles
        float*  chains = (float*)((char*)d_ws + ktab_bytes + 64);    // 8 floats

        zero_fast<<<1, 64, 0, stream>>>(diag, chains);
        diag7<<<1024, 256, 0, stream>>>(w, alpha, diag, n);
        dim3 ga((unsigned)ntiles, 4);
        passA_kernel<<<ga, 256, 0, stream>>>(w, alpha, Ktab, n, ntiles);
        walk_kernel<<<1, 512, 0, stream>>>(w, alpha, Ktab, chains, n, ntiles);
        fin_fast<<<1, 1, 0, stream>>>(chains, diag, alpha, out, n);
    } else {
        float*  chains = (float*)d_ws;
        double* diag   = (double*)((char*)d_ws + 128);
        zero_diag6<<<1, 64, 0, stream>>>(diag);
        diag6<<<1024, 256, 0, stream>>>(w, alpha, diag, (int)(n >> 2), n);
        seq_chains<<<1, 64, 0, stream>>>(w, alpha, chains, n);
        fin_seq<<<1, 1, 0, stream>>>(chains, diag, alpha, out, n);
    }
}

// Round 9
// 753.431 us; speedup vs baseline: 977.5946x; 2.2539x over previous
//
#include <hip/hip_runtime.h>
#include <cstdint>

#define TS 16384           // elements per tile
#define NE 24              // binade slots per chain
#define NCH 7
#define NPART 1024
#define PBT 256

// chains: 0:s(-2) 1:s(-1) 2:s(+1) 3:q(-2) 4:q(-1) 5:q(0) 6:q(+1)
constexpr int H_CBIN[NCH] = {-2,-1, 1,-2,-1, 0, 1};
constexpr int H_CISQ[NCH] = { 0, 0, 0, 1, 1, 1, 1};
constexpr int H_CE0 [NCH] = { 2, 2, 2, 0, 0, 0, 0};

constexpr float p2f(int k) {
    return k >= 0 ? (float)(1ULL << k) : 1.0f / (float)(1ULL << (-k));
}

__device__ __forceinline__ int binof(float x, float a) {
    float r  = __fdiv_rn(x, a);
    float cl = fminf(1.0f, fmaxf(-2.0f, r));
    return (int)rintf(cl);
}

// exact threshold classification == round(clip(x/a)):
// fl(v)>0.5  <=> v >  0.5+2^-25 ; fl(v)<=-1.5 <=> v <= -(1.5-2^-24)
// both a*(...) products exact in f64 (24b x 26b mantissa)
__device__ __forceinline__ int kbin_th(float x, double T1, double T2) {
    double xd = (double)x;
    if (xd >   T1) return 1;
    if (xd >= -T1) return 0;
    if (xd >  -T2) return -1;
    return -2;
}

__device__ __forceinline__ double wred64(double v) {
#pragma unroll
    for (int d = 32; d >= 1; d >>= 1) v += __shfl_xor(v, d, 64);
    return v;
}
__device__ __forceinline__ int wred32i(int v) {
#pragma unroll
    for (int d = 32; d >= 1; d >>= 1) v += __shfl_xor(v, d, 64);
    return v;
}

// =======================================================================
// TIER 1: partition pipeline
// ws: [Ktab][hist][bbase][hdr(cnt4,base4)][diag f64x8][chains f32x8][streams]
// =======================================================================

__global__ __launch_bounds__(64) void zero2(double* __restrict__ diag,
                                            float* __restrict__ chains) {
    if (threadIdx.x < 8) diag[threadIdx.x] = 0.0;
    if (threadIdx.x < 8) chains[threadIdx.x] = 0.0f;
}

__global__ __launch_bounds__(PBT) void part1(const float* __restrict__ w,
        const float* __restrict__ alpha, int* __restrict__ hist,
        double* __restrict__ diag, long long n, long long nseg)
{
    const float a = alpha[0];
    const double T1 = (double)a * (0.5 + 0x1p-25);
    const double T2 = (double)a * (1.5 - 0x1p-24);
    const long long seg = (long long)blockIdx.x * nseg;
    long long send = seg + nseg; if (send > n) send = n;
    int h0=0,h1=0,h2=0,h3=0;
    double ad=0.0, dd=0.0, s0=0.0;

    for (long long i = seg + (long long)threadIdx.x*4; i < send; i += PBT*4) {
        float4 v;
        if (i + 3 < send) v = *reinterpret_cast<const float4*>(w + i);
        else {
            v = make_float4(0.f,0.f,0.f,0.f);
            v.x = w[i];
            if (i+1 < send) v.y = w[i+1];
            if (i+2 < send) v.z = w[i+2];
        }
        const float xs[4] = {v.x, v.y, v.z, v.w};
        const int nv = (int)((send - i) < 4 ? (send - i) : 4);
#pragma unroll
        for (int j = 0; j < 4; ++j) {
            if (j >= nv) break;
            const float x = xs[j];
            const int k = kbin_th(x, T1, T2);
            h0 += (k==-2); h1 += (k==-1); h2 += (k==0); h3 += (k==1);
            const float bf = (float)k;
            const float wq = __fmul_rn(bf, a);
            const float d  = __fsub_rn(x, wq);
            ad += (double)fabsf(d);
            dd += (double)__fmul_rn(d, d);
            if (k == 0) s0 += (double)x;
        }
    }

    h0 = wred32i(h0); h1 = wred32i(h1); h2 = wred32i(h2); h3 = wred32i(h3);
    ad = wred64(ad);  dd = wred64(dd);  s0 = wred64(s0);

    __shared__ int    ih[4][4];
    __shared__ double dh[4][3];
    const int lane = threadIdx.x & 63, wv = threadIdx.x >> 6;
    if (lane == 0) {
        ih[wv][0]=h0; ih[wv][1]=h1; ih[wv][2]=h2; ih[wv][3]=h3;
        dh[wv][0]=ad; dh[wv][1]=dd; dh[wv][2]=s0;
    }
    __syncthreads();
    if (threadIdx.x < 4)
        hist[blockIdx.x*4 + threadIdx.x] =
            ih[0][threadIdx.x]+ih[1][threadIdx.x]+ih[2][threadIdx.x]+ih[3][threadIdx.x];
    if (threadIdx.x == 4) atomicAdd(&diag[0], dh[0][0]+dh[1][0]+dh[2][0]+dh[3][0]);
    if (threadIdx.x == 5) atomicAdd(&diag[1], dh[0][1]+dh[1][1]+dh[2][1]+dh[3][1]);
    if (threadIdx.x == 6) atomicAdd(&diag[2], dh[0][2]+dh[1][2]+dh[2][2]+dh[3][2]);
}

__global__ __launch_bounds__(256) void scank(const int* __restrict__ hist,
        int* __restrict__ bbase, int* __restrict__ hdr)
{
    const int wv = threadIdx.x >> 6, lane = threadIdx.x & 63;
    if (wv < 4) {
        int running = 0;
        for (int c = 0; c < NPART/64; ++c) {
            int v = hist[(c*64 + lane)*4 + wv];
            int p = v;
#pragma unroll
            for (int d = 1; d < 64; d <<= 1) {
                int t = __shfl_up(p, d, 64);
                if (lane >= d) p += t;
            }
            bbase[(c*64+lane)*4 + wv] = running + p - v;
            running += __shfl(p, 63, 64);
        }
        if (lane == 0) hdr[wv] = running;      // cnt[b]
    }
    __syncthreads();
    if (threadIdx.x == 0) {                     // base[b], 64-elem aligned
        int b = 0;
        for (int q = 0; q < 4; ++q) { hdr[4+q] = b; b += (hdr[q] + 63) & ~63; }
    }
}

__global__ __launch_bounds__(PBT) void part2(const float* __restrict__ w,
        const float* __restrict__ alpha, const int* __restrict__ bbase,
        const int* __restrict__ hdr, float* __restrict__ streams,
        long long n, long long nseg)
{
    const float a = alpha[0];
    const double T1 = (double)a * (0.5 + 0x1p-25);
    const double T2 = (double)a * (1.5 - 0x1p-24);
    __shared__ int run[4];
    __shared__ int wtot[4][4];
    const int tid = threadIdx.x, wv = tid >> 6, lane = tid & 63;
    if (tid < 4) run[tid] = hdr[4+tid] + bbase[blockIdx.x*4 + tid];
    __syncthreads();

    const long long seg = (long long)blockIdx.x * nseg;
    long long send = seg + nseg; if (send > n) send = n;

    for (long long base = seg; base < send; base += PBT*4) {
        const long long i = base + (long long)tid*4;
        float xs[4]; int kk[4];
        int c0=0,c1=0,c2=0,c3=0;
        if (i < send) {
            float4 v;
            if (i + 3 < send) v = *reinterpret_cast<const float4*>(w + i);
            else {
                v = make_float4(0.f,0.f,0.f,0.f);
                v.x = w[i];
                if (i+1 < send) v.y = w[i+1];
                if (i+2 < send) v.z = w[i+2];
            }
            xs[0]=v.x; xs[1]=v.y; xs[2]=v.z; xs[3]=v.w;
            const int nv = (int)((send - i) < 4 ? (send - i) : 4);
#pragma unroll
            for (int j = 0; j < 4; ++j) {
                kk[j] = (j < nv) ? kbin_th(xs[j], T1, T2) : 9;
                c0 += (kk[j]==-2); c1 += (kk[j]==-1);
                c2 += (kk[j]==0);  c3 += (kk[j]==1);
            }
        } else { kk[0]=kk[1]=kk[2]=kk[3]=9; xs[0]=xs[1]=xs[2]=xs[3]=0.f; }

        // exclusive wave prefix per bin + totals
        int p0=c0,p1=c1,p2=c2,p3=c3;
#pragma unroll
        for (int d = 1; d < 64; d <<= 1) {
            int t0=__shfl_up(p0,d,64), t1=__shfl_up(p1,d,64);
            int t2=__shfl_up(p2,d,64), t3=__shfl_up(p3,d,64);
            if (lane >= d) { p0+=t0; p1+=t1; p2+=t2; p3+=t3; }
        }
        const int q0=__shfl(p0,63,64), q1=__shfl(p1,63,64);
        const int q2=__shfl(p2,63,64), q3=__shfl(p3,63,64);
        p0-=c0; p1-=c1; p2-=c2; p3-=c3;
        if (lane == 0) { wtot[wv][0]=q0; wtot[wv][1]=q1; wtot[wv][2]=q2; wtot[wv][3]=q3; }
        __syncthreads();
        int o0=run[0], o1=run[1], o2=run[2], o3=run[3];
        for (int ww = 0; ww < wv; ++ww) {
            o0+=wtot[ww][0]; o1+=wtot[ww][1]; o2+=wtot[ww][2]; o3+=wtot[ww][3];
        }
        o0+=p0; o1+=p1; o2+=p2; o3+=p3;
#pragma unroll
        for (int j = 0; j < 4; ++j) {
            const int k = kk[j];
            if (k == 9) continue;
            int off;
            if      (k==-2) off = o0++;
            else if (k==-1) off = o1++;
            else if (k== 0) off = o2++;
            else            off = o3++;
            streams[off] = xs[j];
        }
        __syncthreads();
        if (tid < 4) {
            int s = wtot[0][tid]+wtot[1][tid]+wtot[2][tid]+wtot[3][tid];
            run[tid] += s;
        }
        __syncthreads();
    }
}

// ---- per-chain slot sums on compacted streams (zero divergence) ----
template<int ISQT, int E0T>
__device__ __forceinline__ void passA_one(const float* __restrict__ p,
        long long cnt, double* __restrict__ krow, long long ntg, long long tile)
{
    const long long lo = tile * TS;
    long long hi = lo + TS; if (hi > cnt) hi = cnt;
    double acc[NE];
#pragma unroll
    for (int s = 0; s < NE; ++s) acc[s] = 0.0;

    const int tid = threadIdx.x;
    for (long long i = lo + (long long)tid*4; i < hi; i += 256*4) {
        float4 v;
        if (i + 3 < hi) v = *reinterpret_cast<const float4*>(p + i);
        else {
            v = make_float4(0.f,0.f,0.f,0.f);
            v.x = p[i];
            if (i+1 < hi) v.y = p[i+1];
            if (i+2 < hi) v.z = p[i+2];
        }
        const float xs[4] = {v.x, v.y, v.z, v.w};
#pragma unroll
        for (int j = 0; j < 4; ++j) {
            const float x = xs[j];
            const float xv = ISQT ? __fmul_rn(x, x) : fabsf(x);
#pragma unroll
            for (int s = 0; s < NE; ++s)
                acc[s] += (double)rintf(xv * p2f(23 - E0T - s));
        }
    }

    __shared__ double lred[4][NE];
    const int lane = tid & 63, wv = tid >> 6;
#pragma unroll
    for (int s = 0; s < NE; ++s) {
        double r = wred64(acc[s]);
        if (lane == 0) lred[wv][s] = r;
    }
    __syncthreads();
    if (tid < NE)
        krow[(long long)tid * ntg + tile] =
            lred[0][tid]+lred[1][tid]+lred[2][tid]+lred[3][tid];
}

__global__ __launch_bounds__(256) void passA7(const float* __restrict__ streams,
        const int* __restrict__ hdr, double* __restrict__ Ktab, long long ntg)
{
    const int ch = blockIdx.y;
    const int STR[NCH] = {0,1,3,0,1,2,3};
    const int st = STR[ch];
    const long long cnt = (long long)hdr[st];
    const long long tile = blockIdx.x;
    if (tile * TS >= cnt) return;
    const float* p = streams + hdr[4+st];
    double* krow = Ktab + (long long)ch * NE * ntg;
    switch (ch) {
        case 0: case 1: case 2: passA_one<0,2>(p, cnt, krow, ntg, tile); break;
        default:                passA_one<1,0>(p, cnt, krow, ntg, tile); break;
    }
}

// ---- exact span walker on a stream (no classify) ----
__device__ void span_st(const float* __restrict__ p, float /*unused*/, int isq,
                        double& A, long long lo, long long hi, int lane)
{
    for (long long base = lo; base < hi; base += 4096) {
        float xs[64];
        const long long e0 = base + (long long)lane * 64;
#pragma unroll
        for (int q4 = 0; q4 < 16; ++q4) {
            const long long fi = e0 + q4 * 4;
            float4 v = make_float4(0.f,0.f,0.f,0.f);
            if (fi + 3 < hi) v = *reinterpret_cast<const float4*>(p + fi);
            else {
                if (fi     < hi) v.x = p[fi];
                if (fi + 1 < hi) v.y = p[fi + 1];
                if (fi + 2 < hi) v.z = p[fi + 2];
            }
            xs[q4*4+0]=v.x; xs[q4*4+1]=v.y; xs[q4*4+2]=v.z; xs[q4*4+3]=v.w;
        }
#pragma unroll
        for (int j = 0; j < 64; ++j) {
            const float x = xs[j];
            xs[j] = isq ? __fmul_rn(x, x) : fabsf(x);
        }

        int C = 0;
        while (C < 64) {
            if (A > 0.0) {
                const int e = ilogb(A);
                const double u  = ldexp(1.0, e - 23);
                const double Bb = ldexp(1.0, e + 1);
                const double sc = ldexp(1.0, 23 - e);
                double kd = 0.0;
                if (lane >= C) {
#pragma unroll
                    for (int j = 0; j < 64; ++j) kd += rint((double)xs[j] * sc);
                }
                const bool big = kd >= 1099511627776.0;   // 2^40
                double pp = kd;
#pragma unroll
                for (int d = 1; d < 64; d <<= 1) {
                    double tt = __shfl_up(pp, d, 64);
                    if (lane >= d) pp += tt;
                }
                const bool cross = (lane >= C) && (big || (A + u * pp >= Bb));
                const unsigned long long bal = __ballot(cross);
                if (bal == 0ULL) {
                    A = A + u * __shfl(pp, 63);
                    break;
                }
                const int F = __ffsll((long long)bal) - 1;
                double An = 0.0;
                if (lane == F) {
                    const double Aex = A + u * (pp - kd);
                    float Af = (float)Aex;
#pragma unroll
                    for (int j = 0; j < 64; ++j) Af = __fadd_rn(Af, xs[j]);
                    An = (double)Af;
                }
                A = __shfl(An, F);
                C = F + 1;
            } else {
                bool has = false;
                if (lane >= C) {
#pragma unroll
                    for (int j = 0; j < 64; ++j) has = has || (xs[j] > 0.0f);
                }
                const unsigned long long bal = __ballot(has);
                if (bal == 0ULL) break;
                const int F = __ffsll((long long)bal) - 1;
                double An = 0.0;
                if (lane == F) {
                    float Af = 0.0f;
#pragma unroll
                    for (int j = 0; j < 64; ++j) Af = __fadd_rn(Af, xs[j]);
                    An = (double)Af;
                }
                A = __shfl(An, F);
                C = F + 1;
            }
        }
    }
}

__global__ __launch_bounds__(64) void walk2(const float* __restrict__ streams,
        const int* __restrict__ hdr, const double* __restrict__ Ktab,
        float* __restrict__ chains, long long ntg)
{
    const int ch = blockIdx.x;
    const int lane = threadIdx.x;
    const int STR[NCH]  = {0,1,3,0,1,2,3};
    const int ISQ[NCH]  = {0,0,0,1,1,1,1};
    const int E0c[NCH]  = {2,2,2,0,0,0,0};
    const int OSLOT[NCH]= {0,1,3,4,5,6,7};
    const int st = STR[ch], isq = ISQ[ch], E0 = E0c[ch];
    const long long cnt = (long long)hdr[st];
    const float* p = streams + hdr[4+st];
    const long long ntiles = (cnt + TS - 1) / TS;
    const double* krow = Ktab + (long long)ch * NE * ntg;

    double A = 0.0;
    if (cnt > 0)
        span_st(p, 0.f, isq, A, 0LL, (TS < cnt ? (long long)TS : cnt), lane);

    long long t = 1;
    while (t < ntiles) {
        if (A > 0.0) {
            const int e = ilogb(A);
            const int slot = e - E0;
            if (slot >= 0 && slot < NE) {
                const long long wt = t + lane;
                double Kv = (wt < ntiles) ? krow[(long long)slot * ntg + wt] : 0.0;
                double P = Kv;
#pragma unroll
                for (int d = 1; d < 64; d <<= 1) {
                    double tt = __shfl_up(P, d, 64);
                    if (lane >= d) P += tt;
                }
                const double u  = ldexp(1.0, e - 23);
                const double Bb = ldexp(1.0, e + 1);
                const bool bad = (A + u * P > Bb);
                const unsigned long long bal = __ballot(bad);
                if (bal == 0ULL) { A += u * __shfl(P, 63); t += 64; continue; }
                const int F = __ffsll((long long)bal) - 1;
                if (F > 0) { A += u * __shfl(P, F - 1); t += F; }
                const long long lo = t * (long long)TS;
                long long hi = lo + TS; if (hi > cnt) hi = cnt;
                span_st(p, 0.f, isq, A, lo, hi, lane);
                ++t;
                continue;
            }
        }
        const long long lo = t * (long long)TS;
        long long hi = lo + TS; if (hi > cnt) hi = cnt;
        span_st(p, 0.f, isq, A, lo, hi, lane);
        ++t;
    }
    if (lane == 0) chains[OSLOT[ch]] = (float)A;
}

__global__ void fin2(const float* __restrict__ chains,
                     const double* __restrict__ diag,
                     const int* __restrict__ hdr,
                     const float* __restrict__ alpha,
                     float* __restrict__ out, long long n)
{
    const float a = alpha[0];
    const float s_np[4]  = { -chains[0], -chains[1], (float)diag[2], chains[3] };
    const float sq_np[4] = {  chains[4],  chains[5],  chains[6],     chains[7] };
    float tmse = 0.f, tvar = 0.f;
#pragma unroll
    for (int b = 0; b < 4; ++b) {
        float cnt = fminf((float)hdr[b], 16777216.0f);
        float safe = fmaxf(cnt, 1.0f);
        float mean = __fdiv_rn(s_np[b], safe);
        float var  = __fsub_rn(__fdiv_rn(sq_np[b], safe), __fmul_rn(mean, mean));
        float lvl  = __fmul_rn((float)(b - 2), a);
        float e    = __fsub_rn(mean, lvl);
        if (cnt > 0.f)  tmse = __fadd_rn(tmse, __fmul_rn(e, e));
        if (cnt >= 2.f) tvar = __fadd_rn(tvar, var);
    }
    out[0] = __fadd_rn(tmse, tvar);
    out[1] = tmse;
    out[2] = tvar;
    out[3] = (float)(diag[1] / (double)n);
    out[4] = (float)(diag[0] / (double)n);
}

// =======================================================================
// TIER 2: R8 path (proven bit-exact) — used when ws too small for streams
// =======================================================================

__global__ __launch_bounds__(64) void zero_fast(double* __restrict__ diag,
                                                float* __restrict__ chains) {
    if (threadIdx.x < 8) diag[threadIdx.x] = 0.0;
    if (threadIdx.x < 8) chains[threadIdx.x] = 0.0f;
}

__global__ __launch_bounds__(256) void diag7(const float* __restrict__ w,
        const float* __restrict__ alpha, double* __restrict__ diag, long long n)
{
    const float a = alpha[0];
    double ad = 0.0, dd = 0.0, s0 = 0.0;
    int c0 = 0, c1 = 0, c2 = 0, c3 = 0;
    auto pe = [&](float x) {
        float r  = __fdiv_rn(x, a);
        float cl = fminf(1.0f, fmaxf(-2.0f, r));
        float bf = rintf(cl);
        int   k  = (int)bf;
        float wq = __fmul_rn(bf, a);
        float d  = __fsub_rn(x, wq);
        ad += (double)fabsf(d);
        dd += (double)__fmul_rn(d, d);
        if (k == 0) s0 += (double)x;
        if      (k == -2) c0++;
        else if (k == -1) c1++;
        else if (k ==  0) c2++;
        else              c3++;
    };
    const long long n4 = n >> 2;
    const float4* __restrict__ w4 = reinterpret_cast<const float4*>(w);
    const long long stride = (long long)gridDim.x * 256;
    for (long long i = (long long)blockIdx.x * 256 + threadIdx.x; i < n4; i += stride) {
        float4 v = w4[i];
        pe(v.x); pe(v.y); pe(v.z); pe(v.w);
    }
    if (blockIdx.x == 0 && threadIdx.x == 0)
        for (long long i = n4 << 2; i < n; ++i) pe(w[i]);

    double vals[7] = {ad, dd, (double)c0, (double)c1, (double)c2, (double)c3, s0};
    __shared__ double red[256];
    const int tid = threadIdx.x;
#pragma unroll
    for (int j = 0; j < 7; ++j) {
        red[tid] = vals[j];
        __syncthreads();
        for (int s = 128; s > 0; s >>= 1) {
            if (tid < s) red[tid] += red[tid + s];
            __syncthreads();
        }
        if (tid == 0) atomicAdd(&diag[j + 1], red[0]);   // diag[1..7]
        __syncthreads();
    }
}

template<int CA, int CB>
__device__ __forceinline__ void passA_body(const float* __restrict__ w, float a,
        double* __restrict__ Ktab, long long n, long long ntiles)
{
    constexpr int BA  = H_CBIN[CA];
    constexpr int QA  = H_CISQ[CA];
    constexpr int E0A = H_CE0[CA];
    constexpr int BB  = (CB >= 0) ? H_CBIN[CB] : 99;
    constexpr int QB  = (CB >= 0) ? H_CISQ[CB] : 0;
    constexpr int E0B = (CB >= 0) ? H_CE0[CB] : 0;

    const long long tile = blockIdx.x;
    const int tid = threadIdx.x;
    int accA[NE], accB[NE];
#pragma unroll
    for (int s = 0; s < NE; ++s) { accA[s] = 0; accB[s] = 0; }

    const long long base4 = tile * (TS / 4);
#pragma unroll 1
    for (int i = 0; i < TS / (4 * 256); ++i) {
        const long long fi4 = base4 + (long long)i * 256 + tid;
        const long long fe  = fi4 * 4;
        float4 v = make_float4(0.f, 0.f, 0.f, 0.f);
        if (fe + 3 < n) v = *reinterpret_cast<const float4*>(w + fe);
        else if (fe < n) {
            v.x = w[fe];
            if (fe + 1 < n) v.y = w[fe + 1];
            if (fe + 2 < n) v.z = w[fe + 2];
        }
        const float e4[4] = {v.x, v.y, v.z, v.w};
#pragma unroll
        for (int j = 0; j < 4; ++j) {
            const float x = e4[j];
            const int b = binof(x, a);
            if (b == BA) {
                const float xv = QA ? __fmul_rn(x, x) : fabsf(x);
#pragma unroll
                for (int s = 0; s < NE; ++s)
                    accA[s] += (int)rintf(xv * p2f(23 - E0A - s));
            } else if (CB >= 0 && b == BB) {
                const float xv = QB ? __fmul_rn(x, x) : fabsf(x);
#pragma unroll
                for (int s = 0; s < NE; ++s)
                    accB[s] += (int)rintf(xv * p2f(23 - E0B - s));
            }
        }
    }

    __shared__ double lred[4][2 * NE];
    const int lane = tid & 63, wid = tid >> 6;
#pragma unroll
    for (int s = 0; s < NE; ++s) {
        double va = wred64((double)accA[s]);
        double vb = wred64((double)accB[s]);
        if (lane == 0) { lred[wid][s] = va; lred[wid][NE + s] = vb; }
    }
    __syncthreads();
    if (tid < 2 * NE) {
        const double sum = lred[0][tid] + lred[1][tid] + lred[2][tid] + lred[3][tid];
        const int c = (tid < NE) ? CA : CB;
        const int s = (tid < NE) ? tid : tid - NE;
        if (c >= 0)
            Ktab[((long long)(c * NE + s)) * ntiles + tile] = sum;
    }
}

__global__ __launch_bounds__(256) void passA_kernel(const float* __restrict__ w,
        const float* __restrict__ alpha, double* __restrict__ Ktab,
        long long n, long long ntiles)
{
    const float a = alpha[0];
    switch (blockIdx.y) {
        case 0:  passA_body<0, 1>(w, a, Ktab, n, ntiles); break;
        case 1:  passA_body<2, 3>(w, a, Ktab, n, ntiles); break;
        case 2:  passA_body<4, 5>(w, a, Ktab, n, ntiles); break;
        default: passA_body<6,-1>(w, a, Ktab, n, ntiles); break;
    }
}

__device__ void walk_span2(const float* __restrict__ w, long long n, float a,
                           int mybin, int myisq, double& A,
                           long long lo, long long hi, int lane)
{
    for (long long base = lo; base < hi; base += 4096) {
        float xs[64];
        const long long e0 = base + (long long)lane * 64;
#pragma unroll
        for (int q4 = 0; q4 < 16; ++q4) {
            const long long fi = e0 + q4 * 4;
            float4 v = make_float4(0.f, 0.f, 0.f, 0.f);
            if (fi + 3 < n) v = *reinterpret_cast<const float4*>(w + fi);
            else {
                if (fi     < n) v.x = w[fi];
                if (fi + 1 < n) v.y = w[fi + 1];
                if (fi + 2 < n) v.z = w[fi + 2];
            }
            xs[q4*4+0]=v.x; xs[q4*4+1]=v.y; xs[q4*4+2]=v.z; xs[q4*4+3]=v.w;
        }
#pragma unroll
        for (int j = 0; j < 64; ++j) {
            const float x = xs[j];
            float xv = 0.0f;
            if (binof(x, a) == mybin) xv = myisq ? __fmul_rn(x, x) : fabsf(x);
            xs[j] = xv;
        }
        int C = 0;
        while (C < 64) {
            if (A > 0.0) {
                const int e = ilogb(A);
                const double u  = ldexp(1.0, e - 23);
                const double Bb = ldexp(1.0, e + 1);
                const double sc = ldexp(1.0, 23 - e);
                double kd = 0.0;
                if (lane >= C) {
#pragma unroll
                    for (int j = 0; j < 64; ++j) kd += rint((double)xs[j] * sc);
                }
                const bool big = kd >= 1099511627776.0;
                double p = kd;
#pragma unroll
                for (int d = 1; d < 64; d <<= 1) {
                    double tt = __shfl_up(p, d, 64);
                    if (lane >= d) p += tt;
                }
                const bool cross = (lane >= C) && (big || (A + u * p >= Bb));
                const unsigned long long bal = __ballot(cross);
                if (bal == 0ULL) { A = A + u * __shfl(p, 63); break; }
                const int F = __ffsll((long long)bal) - 1;
                double An = 0.0;
                if (lane == F) {
                    const double Aex = A + u * (p - kd);
                    float Af = (float)Aex;
#pragma unroll
                    for (int j = 0; j < 64; ++j) Af = __fadd_rn(Af, xs[j]);
                    An = (double)Af;
                }
                A = __shfl(An, F);
                C = F + 1;
            } else {
                bool has = false;
                if (lane >= C) {
#pragma unroll
                    for (int j = 0; j < 64; ++j) has = has || (xs[j] > 0.0f);
                }
                const unsigned long long bal = __ballot(has);
                if (bal == 0ULL) break;
                const int F = __ffsll((long long)bal) - 1;
                double An = 0.0;
                if (lane == F) {
                    float Af = 0.0f;
#pragma unroll
                    for (int j = 0; j < 64; ++j) Af = __fadd_rn(Af, xs[j]);
                    An = (double)Af;
                }
                A = __shfl(An, F);
                C = F + 1;
            }
        }
    }
}

__global__ __launch_bounds__(512) void walk_kernel(const float* __restrict__ w,
        const float* __restrict__ alpha, const double* __restrict__ Ktab,
        float* __restrict__ chains, long long n, long long ntiles)
{
    const int wave = threadIdx.x >> 6;
    const int lane = threadIdx.x & 63;
    if (wave >= NCH) return;
    const int ch = wave;
    const int CBIN[NCH] = {-2,-1, 1,-2,-1, 0, 1};
    const int CISQ[NCH] = { 0, 0, 0, 1, 1, 1, 1};
    const int CE0 [NCH] = { 2, 2, 2, 0, 0, 0, 0};
    const int OSLOT[NCH]= { 0, 1, 3, 4, 5, 6, 7};
    const int mybin = CBIN[ch], myisq = CISQ[ch], E0 = CE0[ch];
    const float a = alpha[0];

    double A = 0.0;
    walk_span2(w, n, a, mybin, myisq, A, 0LL, (TS < n ? (long long)TS : n), lane);

    long long t = 1;
    while (t < ntiles) {
        if (A > 0.0) {
            const int e = ilogb(A);
            const int slot = e - E0;
            if (slot >= 0 && slot < NE) {
                const long long wt = t + lane;
                double Kv = (wt < ntiles)
                          ? Ktab[((long long)(ch * NE + slot)) * ntiles + wt] : 0.0;
                double P = Kv;
#pragma unroll
                for (int d = 1; d < 64; d <<= 1) {
                    double tt = __shfl_up(P, d, 64);
                    if (lane >= d) P += tt;
                }
                const double u  = ldexp(1.0, e - 23);
                const double Bb = ldexp(1.0, e + 1);
                const bool bad = (A + u * P > Bb);
                const unsigned long long bal = __ballot(bad);
                if (bal == 0ULL) { A += u * __shfl(P, 63); t += 64; continue; }
                const int F = __ffsll((long long)bal) - 1;
                if (F > 0) { A += u * __shfl(P, F - 1); t += F; }
                const long long lo = t * (long long)TS;
                const long long hi = (lo + TS < n) ? lo + TS : n;
                walk_span2(w, n, a, mybin, myisq, A, lo, hi, lane);
                ++t;
                continue;
            }
        }
        const long long lo = t * (long long)TS;
        const long long hi = (lo + TS < n) ? lo + TS : n;
        walk_span2(w, n, a, mybin, myisq, A, lo, hi, lane);
        ++t;
    }
    if (lane == 0) chains[OSLOT[ch]] = (float)A;
}

__global__ void fin_fast(const float* __restrict__ chains,
                         const double* __restrict__ diag,
                         const float* __restrict__ alpha,
                         float* __restrict__ out, long long n)
{
    const float a = alpha[0];
    const float s_np[4]  = { -chains[0], -chains[1], (float)diag[7], chains[3] };
    const float sq_np[4] = {  chains[4],  chains[5],  chains[6],     chains[7] };
    float tmse = 0.f, tvar = 0.f;
#pragma unroll
    for (int b = 0; b < 4; ++b) {
        float cnt = fminf((float)diag[3 + b], 16777216.0f);
        float safe = fmaxf(cnt, 1.0f);
        float mean = __fdiv_rn(s_np[b], safe);
        float var  = __fsub_rn(__fdiv_rn(sq_np[b], safe), __fmul_rn(mean, mean));
        float lvl  = __fmul_rn((float)(b - 2), a);
        float e    = __fsub_rn(mean, lvl);
        if (cnt > 0.f)  tmse = __fadd_rn(tmse, __fmul_rn(e, e));
        if (cnt >= 2.f) tvar = __fadd_rn(tvar, var);
    }
    out[0] = __fadd_rn(tmse, tvar);
    out[1] = tmse;
    out[2] = tvar;
    out[3] = (float)(diag[2] / (double)n);
    out[4] = (float)(diag[1] / (double)n);
}

// ================= TIER 3: R6 bit-exact serial =================
__global__ __launch_bounds__(64) void zero_diag6(double* __restrict__ diag) {
    if (threadIdx.x < 6) diag[threadIdx.x] = 0.0;
}
__global__ __launch_bounds__(256) void diag6(const float* __restrict__ w,
        const float* __restrict__ alpha, double* __restrict__ diag, int n4, long long n)
{
    const float a = alpha[0];
    float ad = 0.f, dd = 0.f; int c0=0,c1=0,c2=0,c3=0;
    auto pe = [&](float x) {
        float r = __fdiv_rn(x, a);
        float cl = fminf(1.0f, fmaxf(-2.0f, r));
        float bf = rintf(cl); int k = (int)bf;
        float wq = __fmul_rn(bf, a); float d = __fsub_rn(x, wq);
        ad = __fadd_rn(ad, fabsf(d)); dd = __fadd_rn(dd, __fmul_rn(d, d));
        if (k==-2) c0++; else if (k==-1) c1++; else if (k==0) c2++; else c3++;
    };
    const float4* w4 = reinterpret_cast<const float4*>(w);
    const int stride = gridDim.x * 256;
    for (int i = blockIdx.x * 256 + threadIdx.x; i < n4; i += stride) {
        float4 v = w4[i]; pe(v.x); pe(v.y); pe(v.z); pe(v.w);
    }
    if (blockIdx.x == 0 && threadIdx.x == 0)
        for (long long i = (long long)n4 * 4; i < n; ++i) pe(w[i]);
    double vals[6] = {(double)ad,(double)dd,(double)c0,(double)c1,(double)c2,(double)c3};
    __shared__ double red[256];
    const int tid = threadIdx.x;
#pragma unroll
    for (int j = 0; j < 6; ++j) {
        red[tid] = vals[j]; __syncthreads();
        for (int s = 128; s > 0; s >>= 1) { if (tid < s) red[tid] += red[tid+s]; __syncthreads(); }
        if (tid == 0) atomicAdd(&diag[j], red[0]);
        __syncthreads();
    }
}
__global__ __launch_bounds__(64) void seq_chains(const float* __restrict__ w,
        const float* __restrict__ alpha, float* __restrict__ chains, long long n)
{
    const float a = alpha[0];
    const int lane = threadIdx.x; const int myrow = lane & 7;
    __shared__ float val[8][64];
    float acc = 0.0f;
    const long long ntl = (n + 63) / 64;
    float x_next = (lane < n) ? w[lane] : 0.0f;
    for (long long t = 0; t < ntl; ++t) {
        float x = x_next;
        { long long idxn = (t + 1) * 64 + lane; x_next = (idxn < n) ? w[idxn] : 0.0f; }
        const long long idx = t * 64 + lane;
        const bool valid = (idx < n);
        float r = __fdiv_rn(x, a);
        float cl = fminf(1.0f, fmaxf(-2.0f, r));
        int k = (int)rintf(cl); int row = k + 2;
        float xx = __fmul_rn(x, x);
#pragma unroll
        for (int b = 0; b < 4; ++b) {
            val[b][lane]     = (valid && row == b) ? x  : 0.0f;
            val[4 + b][lane] = (valid && row == b) ? xx : 0.0f;
        }
        __syncthreads();
        if (lane < 8) {
#pragma unroll
            for (int e4i = 0; e4i < 16; ++e4i) {
                float4 v = *reinterpret_cast<const float4*>(&val[myrow][e4i * 4]);
                acc = __fadd_rn(acc, v.x); acc = __fadd_rn(acc, v.y);
                acc = __fadd_rn(acc, v.z); acc = __fadd_rn(acc, v.w);
            }
        }
        __syncthreads();
    }
    if (lane < 8) chains[lane] = acc;
}
__global__ void fin_seq(const float* __restrict__ chains, const double* __restrict__ diag,
                        const float* __restrict__ alpha, float* __restrict__ out, long long n)
{
    const float a = alpha[0];
    float tmse = 0.0f, tvar = 0.0f;
#pragma unroll
    for (int b = 0; b < 4; ++b) {
        float cnt = fminf((float)diag[2 + b], 16777216.0f);
        float safe = fmaxf(cnt, 1.0f);
        float mean = __fdiv_rn(chains[b], safe);
        float var  = __fsub_rn(__fdiv_rn(chains[4 + b], safe), __fmul_rn(mean, mean));
        float lvl  = __fmul_rn((float)(b - 2), a);
        float e    = __fsub_rn(mean, lvl);
        if (cnt > 0.0f)  tmse = __fadd_rn(tmse, __fmul_rn(e, e));
        if (cnt >= 2.0f) tvar = __fadd_rn(tvar, var);
    }
    out[0] = __fadd_rn(tmse, tvar);
    out[1] = tmse; out[2] = tvar;
    out[3] = (float)(diag[1] / (double)n);
    out[4] = (float)(diag[0] / (double)n);
}

// ---------------- launcher ----------------
extern "C" void kernel_launch(void* const* d_in, const int* in_sizes, int n_in,
                              void* d_out, int out_size, void* d_ws, size_t ws_size,
                              hipStream_t stream) {
    const float* w     = (const float*)d_in[0];
    const float* alpha = (const float*)d_in[1];
    float* out = (float*)d_out;
    const long long n = (long long)in_sizes[0];
    const long long ntg = (n + TS - 1) / TS;

    // tier-1 layout
    size_t off = 0;
    const size_t ktab_off = off;   off += (size_t)NCH * NE * ntg * 8;
    const size_t hist_off = off;   off += (size_t)NPART * 4 * 4;
    const size_t bbase_off = off;  off += (size_t)NPART * 4 * 4;
    const size_t hdr_off = off;    off += 8 * 4;
    const size_t diag_off = (off + 7) & ~(size_t)7;  off = diag_off + 8 * 8;
    const size_t chains_off = off; off += 8 * 4;
    const size_t streams_off = (off + 255) & ~(size_t)255;
    const size_t need1 = streams_off + ((size_t)n + 512) * 4;

    if (ws_size >= need1) {
        double* Ktab   = (double*)((char*)d_ws + ktab_off);
        int*    hist   = (int*)   ((char*)d_ws + hist_off);
        int*    bbase  = (int*)   ((char*)d_ws + bbase_off);
        int*    hdr    = (int*)   ((char*)d_ws + hdr_off);
        double* diag   = (double*)((char*)d_ws + diag_off);
        float*  chains = (float*) ((char*)d_ws + chains_off);
        float*  strm   = (float*) ((char*)d_ws + streams_off);
        long long nseg = ((n + NPART - 1) / NPART + 1023) & ~1023LL;

        zero2<<<1, 64, 0, stream>>>(diag, chains);
        part1<<<NPART, PBT, 0, stream>>>(w, alpha, hist, diag, n, nseg);
        scank<<<1, 256, 0, stream>>>(hist, bbase, hdr);
        part2<<<NPART, PBT, 0, stream>>>(w, alpha, bbase, hdr, strm, n, nseg);
        dim3 ga((unsigned)ntg, NCH);
        passA7<<<ga, 256, 0, stream>>>(strm, hdr, Ktab, ntg);
        walk2<<<NCH, 64, 0, stream>>>(strm, hdr, Ktab, chains, ntg);
        fin2<<<1, 1, 0, stream>>>(chains, diag, hdr, alpha, out, n);
        return;
    }

    const size_t ktab_bytes = (size_t)NCH * NE * ntg * sizeof(double);
    const size_t need2 = ktab_bytes + 128;
    if (ws_size >= need2) {
        double* Ktab   = (double*)d_ws;
        double* diag   = (double*)((char*)d_ws + ktab_bytes);        // 8 doubles
        float*  chains = (float*)((char*)d_ws + ktab_bytes + 64);    // 8 floats
        zero_fast<<<1, 64, 0, stream>>>(diag, chains);
        diag7<<<1024, 256, 0, stream>>>(w, alpha, diag, n);
        dim3 ga((unsigned)ntg, 4);
        passA_kernel<<<ga, 256, 0, stream>>>(w, alpha, Ktab, n, ntg);
        walk_kernel<<<1, 512, 0, stream>>>(w, alpha, Ktab, chains, n, ntg);
        fin_fast<<<1, 1, 0, stream>>>(chains, diag, alpha, out, n);
    } else {
        float*  chains = (float*)d_ws;
        double* diag   = (double*)((char*)d_ws + 128);
        zero_diag6<<<1, 64, 0, stream>>>(diag);
        diag6<<<1024, 256, 0, stream>>>(w, alpha, diag, (int)(n >> 2), n);
        seq_chains<<<1, 64, 0, stream>>>(w, alpha, chains, n);
        fin_seq<<<1, 1, 0, stream>>>(chains, diag, alpha, out, n);
    }
}

// Round 10
// 645.753 us; speedup vs baseline: 1140.6057x; 1.1667x over previous
//
#include <hip/hip_runtime.h>
#include <cstdint>

#define TS 16384           // elements per tile
#define NSLOT 16           // binade slots per chain (relative to e_min)
#define NCH 7
#define NPART 1024
#define PBT 256
#define FLQ 1024           // part2 flush quantum

// chains: 0:s(-2) 1:s(-1) 2:s(+1) 3:q(-2) 4:q(-1) 5:q(0) 6:q(+1)
// s(0) is a non-stalling random walk -> f64 in diag; counts -> min(true,2^24)

__device__ __forceinline__ int kbin_th(float x, double T1, double T2) {
    // exact threshold classification == round(clip(x/a)) [proven R9]
    double xd = (double)x;
    if (xd >   T1) return 1;
    if (xd >= -T1) return 0;
    if (xd >  -T2) return -1;
    return -2;
}

__device__ __forceinline__ double wred64(double v) {
#pragma unroll
    for (int d = 32; d >= 1; d >>= 1) v += __shfl_xor(v, d, 64);
    return v;
}
__device__ __forceinline__ int wred32i(int v) {
#pragma unroll
    for (int d = 32; d >= 1; d >>= 1) v += __shfl_xor(v, d, 64);
    return v;
}

__device__ __forceinline__ int expo_bits(double A) {
    const long long b = __double_as_longlong(A);
    return (int)((b >> 52) & 0x7FF) - 1023;
}
__device__ __forceinline__ int emin_of(double A0) {
    if (!(A0 > 0.0)) return 12345;           // invalid -> walker always spans (exact)
    const int e = expo_bits(A0);
    if (e < -100 || e > 100) return 12345;
    return e;
}

// ---------------- zero ----------------
__global__ __launch_bounds__(64) void zero2(double* __restrict__ diag,
        float* __restrict__ chains, double* __restrict__ A0d) {
    if (threadIdx.x < 8) {
        diag[threadIdx.x] = 0.0;
        chains[threadIdx.x] = 0.0f;
        A0d[threadIdx.x] = 0.0;
    }
}

// ---------------- part1: histogram + diagnostics (proven R9) ----------------
__global__ __launch_bounds__(PBT) void part1(const float* __restrict__ w,
        const float* __restrict__ alpha, int* __restrict__ hist,
        double* __restrict__ diag, long long n, long long nseg)
{
    const float a = alpha[0];
    const double T1 = (double)a * (0.5 + 0x1p-25);
    const double T2 = (double)a * (1.5 - 0x1p-24);
    const long long seg = (long long)blockIdx.x * nseg;
    long long send = seg + nseg; if (send > n) send = n;
    int h0=0,h1=0,h2=0,h3=0;
    double ad=0.0, dd=0.0, s0=0.0;

    for (long long i = seg + (long long)threadIdx.x*4; i < send; i += PBT*4) {
        float4 v;
        if (i + 3 < send) v = *reinterpret_cast<const float4*>(w + i);
        else {
            v = make_float4(0.f,0.f,0.f,0.f);
            v.x = w[i];
            if (i+1 < send) v.y = w[i+1];
            if (i+2 < send) v.z = w[i+2];
        }
        const float xs[4] = {v.x, v.y, v.z, v.w};
        const int nv = (int)((send - i) < 4 ? (send - i) : 4);
#pragma unroll
        for (int j = 0; j < 4; ++j) {
            if (j >= nv) break;
            const float x = xs[j];
            const int k = kbin_th(x, T1, T2);
            h0 += (k==-2); h1 += (k==-1); h2 += (k==0); h3 += (k==1);
            const float bf = (float)k;
            const float wq = __fmul_rn(bf, a);
            const float d  = __fsub_rn(x, wq);
            ad += (double)fabsf(d);
            dd += (double)__fmul_rn(d, d);
            if (k == 0) s0 += (double)x;
        }
    }

    h0 = wred32i(h0); h1 = wred32i(h1); h2 = wred32i(h2); h3 = wred32i(h3);
    ad = wred64(ad);  dd = wred64(dd);  s0 = wred64(s0);

    __shared__ int    ih[4][4];
    __shared__ double dh[4][3];
    const int lane = threadIdx.x & 63, wv = threadIdx.x >> 6;
    if (lane == 0) {
        ih[wv][0]=h0; ih[wv][1]=h1; ih[wv][2]=h2; ih[wv][3]=h3;
        dh[wv][0]=ad; dh[wv][1]=dd; dh[wv][2]=s0;
    }
    __syncthreads();
    if (threadIdx.x < 4)
        hist[blockIdx.x*4 + threadIdx.x] =
            ih[0][threadIdx.x]+ih[1][threadIdx.x]+ih[2][threadIdx.x]+ih[3][threadIdx.x];
    if (threadIdx.x == 4) atomicAdd(&diag[0], dh[0][0]+dh[1][0]+dh[2][0]+dh[3][0]);
    if (threadIdx.x == 5) atomicAdd(&diag[1], dh[0][1]+dh[1][1]+dh[2][1]+dh[3][1]);
    if (threadIdx.x == 6) atomicAdd(&diag[2], dh[0][2]+dh[1][2]+dh[2][2]+dh[3][2]);
}

// ---------------- scank (proven R9) ----------------
__global__ __launch_bounds__(256) void scank(const int* __restrict__ hist,
        int* __restrict__ bbase, int* __restrict__ hdr)
{
    const int wv = threadIdx.x >> 6, lane = threadIdx.x & 63;
    if (wv < 4) {
        int running = 0;
        for (int c = 0; c < NPART/64; ++c) {
            int v = hist[(c*64 + lane)*4 + wv];
            int p = v;
#pragma unroll
            for (int d = 1; d < 64; d <<= 1) {
                int t = __shfl_up(p, d, 64);
                if (lane >= d) p += t;
            }
            bbase[(c*64+lane)*4 + wv] = running + p - v;
            running += __shfl(p, 63, 64);
        }
        if (lane == 0) hdr[wv] = running;      // cnt[b]
    }
    __syncthreads();
    if (threadIdx.x == 0) {                     // base[b], 64-elem aligned
        int b = 0;
        for (int q = 0; q < 4; ++q) { hdr[4+q] = b; b += (hdr[q] + 63) & ~63; }
    }
}

// ---------------- part2: order-preserving partition, LDS-staged flushes ----------------
__global__ __launch_bounds__(PBT) void part2(const float* __restrict__ w,
        const float* __restrict__ alpha, const int* __restrict__ bbase,
        const int* __restrict__ hdr, float* __restrict__ streams,
        long long n, long long nseg)
{
    const float a = alpha[0];
    const double T1 = (double)a * (0.5 + 0x1p-25);
    const double T2 = (double)a * (1.5 - 0x1p-24);
    __shared__ float buf[4][2048];
    __shared__ int run[4], fill[4];
    __shared__ int wtot[4][4];
    const int tid = threadIdx.x, wv = tid >> 6, lane = tid & 63;
    if (tid < 4) { run[tid] = hdr[4+tid] + bbase[blockIdx.x*4 + tid]; fill[tid] = 0; }
    __syncthreads();

    const long long seg = (long long)blockIdx.x * nseg;
    long long send = seg + nseg; if (send > n) send = n;

    for (long long base = seg; base < send; base += PBT*4) {
        const long long i = base + (long long)tid * 4;
        float xs[4]; int kk[4];
        int c0=0,c1=0,c2=0,c3=0;
        if (i < send) {
            float4 v;
            if (i + 3 < send) v = *reinterpret_cast<const float4*>(w + i);
            else {
                v = make_float4(0.f,0.f,0.f,0.f);
                v.x = w[i];
                if (i+1 < send) v.y = w[i+1];
                if (i+2 < send) v.z = w[i+2];
            }
            xs[0]=v.x; xs[1]=v.y; xs[2]=v.z; xs[3]=v.w;
            const int nv = (int)((send - i) < 4 ? (send - i) : 4);
#pragma unroll
            for (int j = 0; j < 4; ++j) {
                kk[j] = (j < nv) ? kbin_th(xs[j], T1, T2) : 9;
                c0 += (kk[j]==-2); c1 += (kk[j]==-1);
                c2 += (kk[j]==0);  c3 += (kk[j]==1);
            }
        } else { kk[0]=kk[1]=kk[2]=kk[3]=9; xs[0]=xs[1]=xs[2]=xs[3]=0.f; }

        // per-bin wave prefix
        int p0=c0,p1=c1,p2=c2,p3=c3;
#pragma unroll
        for (int d = 1; d < 64; d <<= 1) {
            int t0=__shfl_up(p0,d,64), t1=__shfl_up(p1,d,64);
            int t2=__shfl_up(p2,d,64), t3=__shfl_up(p3,d,64);
            if (lane >= d) { p0+=t0; p1+=t1; p2+=t2; p3+=t3; }
        }
        const int q0=__shfl(p0,63,64), q1=__shfl(p1,63,64);
        const int q2=__shfl(p2,63,64), q3=__shfl(p3,63,64);
        p0-=c0; p1-=c1; p2-=c2; p3-=c3;
        if (lane == 0) { wtot[wv][0]=q0; wtot[wv][1]=q1; wtot[wv][2]=q2; wtot[wv][3]=q3; }
        __syncthreads();
        int o0=fill[0], o1=fill[1], o2=fill[2], o3=fill[3];
        for (int ww = 0; ww < wv; ++ww) {
            o0+=wtot[ww][0]; o1+=wtot[ww][1]; o2+=wtot[ww][2]; o3+=wtot[ww][3];
        }
        o0+=p0; o1+=p1; o2+=p2; o3+=p3;
#pragma unroll
        for (int j = 0; j < 4; ++j) {
            const int k = kk[j];
            if (k == 9) continue;
            if      (k==-2) buf[0][o0++] = xs[j];
            else if (k==-1) buf[1][o1++] = xs[j];
            else if (k== 0) buf[2][o2++] = xs[j];
            else            buf[3][o3++] = xs[j];
        }
        __syncthreads();
        if (tid < 4) fill[tid] += wtot[0][tid]+wtot[1][tid]+wtot[2][tid]+wtot[3][tid];
        __syncthreads();

#pragma unroll
        for (int b = 0; b < 4; ++b) {
            if (fill[b] >= FLQ) {                       // block-uniform branch
                const int rem = fill[b] - FLQ;
                // coalesced flush of FLQ elems
#pragma unroll
                for (int r = 0; r < FLQ/PBT; ++r)
                    streams[(long long)run[b] + r*PBT + tid] = buf[b][r*PBT + tid];
                float mv = 0.f;
                if (tid < rem) mv = buf[b][FLQ + tid];
                __syncthreads();
                if (tid < rem) buf[b][tid] = mv;
                if (tid == 0) { run[b] += FLQ; fill[b] = rem; }
                __syncthreads();
            }
        }
    }
    // drain
#pragma unroll
    for (int b = 0; b < 4; ++b) {
        for (int i2 = tid; i2 < fill[b]; i2 += PBT)
            streams[(long long)run[b] + i2] = buf[b][i2];
    }
}

// ---- exact span walker on a stream (proven R9, verbatim semantics) ----
__device__ void span_st(const float* __restrict__ p, int isq,
                        double& A, long long lo, long long hi, int lane)
{
    for (long long base = lo; base < hi; base += 4096) {
        float xs[64];
        const long long e0 = base + (long long)lane * 64;
#pragma unroll
        for (int q4 = 0; q4 < 16; ++q4) {
            const long long fi = e0 + q4 * 4;
            float4 v = make_float4(0.f,0.f,0.f,0.f);
            if (fi + 3 < hi) v = *reinterpret_cast<const float4*>(p + fi);
            else {
                if (fi     < hi) v.x = p[fi];
                if (fi + 1 < hi) v.y = p[fi + 1];
                if (fi + 2 < hi) v.z = p[fi + 2];
            }
            xs[q4*4+0]=v.x; xs[q4*4+1]=v.y; xs[q4*4+2]=v.z; xs[q4*4+3]=v.w;
        }
#pragma unroll
        for (int j = 0; j < 64; ++j) {
            const float x = xs[j];
            xs[j] = isq ? __fmul_rn(x, x) : fabsf(x);
        }

        int C = 0;
        while (C < 64) {
            if (A > 0.0) {
                const int e = ilogb(A);
                const double u  = ldexp(1.0, e - 23);
                const double Bb = ldexp(1.0, e + 1);
                const double sc = ldexp(1.0, 23 - e);
                double kd = 0.0;
                if (lane >= C) {
#pragma unroll
                    for (int j = 0; j < 64; ++j) kd += rint((double)xs[j] * sc);
                }
                const bool big = kd >= 1099511627776.0;   // 2^40
                double pp = kd;
#pragma unroll
                for (int d = 1; d < 64; d <<= 1) {
                    double tt = __shfl_up(pp, d, 64);
                    if (lane >= d) pp += tt;
                }
                const bool cross = (lane >= C) && (big || (A + u * pp >= Bb));
                const unsigned long long bal = __ballot(cross);
                if (bal == 0ULL) {
                    A = A + u * __shfl(pp, 63);
                    break;
                }
                const int F = __ffsll((long long)bal) - 1;
                double An = 0.0;
                if (lane == F) {
                    const double Aex = A + u * (pp - kd);
                    float Af = (float)Aex;
#pragma unroll
                    for (int j = 0; j < 64; ++j) Af = __fadd_rn(Af, xs[j]);
                    An = (double)Af;
                }
                A = __shfl(An, F);
                C = F + 1;
            } else {
                bool has = false;
                if (lane >= C) {
#pragma unroll
                    for (int j = 0; j < 64; ++j) has = has || (xs[j] > 0.0f);
                }
                const unsigned long long bal = __ballot(has);
                if (bal == 0ULL) break;
                const int F = __ffsll((long long)bal) - 1;
                double An = 0.0;
                if (lane == F) {
                    float Af = 0.0f;
#pragma unroll
                    for (int j = 0; j < 64; ++j) Af = __fadd_rn(Af, xs[j]);
                    An = (double)Af;
                }
                A = __shfl(An, F);
                C = F + 1;
            }
        }
    }
}

// ---------------- span0: exact tile-0 chain state per chain ----------------
__global__ __launch_bounds__(64) void span0(const float* __restrict__ streams,
        const int* __restrict__ hdr, double* __restrict__ A0d)
{
    const int ch = blockIdx.x;
    const int STR[NCH] = {0,1,3,0,1,2,3};
    const int ISQ[NCH] = {0,0,0,1,1,1,1};
    const int st = STR[ch];
    const long long cnt = (long long)hdr[st];
    const float* p = streams + hdr[4+st];
    double A = 0.0;
    if (cnt > 0)
        span_st(p, ISQ[ch], A, 0LL, (TS < cnt ? (long long)TS : cnt), threadIdx.x);
    if (threadIdx.x == 0) A0d[ch] = A;
}

// ---------------- passA: 16 e_min-relative slots, int32 accumulators ----------------
template<int ISQT>
__device__ __forceinline__ void passA_one(const float* __restrict__ p,
        long long cnt, double* __restrict__ krow, long long ntg, long long tile,
        float base)
{
    const long long lo = tile * TS;
    long long hi = lo + TS; if (hi > cnt) hi = cnt;

    float scale[NSLOT];
    scale[0] = base;
#pragma unroll
    for (int s = 1; s < NSLOT; ++s) scale[s] = scale[s-1] * 0.5f;  // exact
    int acc[NSLOT];
#pragma unroll
    for (int s = 0; s < NSLOT; ++s) acc[s] = 0;

    const int tid = threadIdx.x;
    for (long long i = lo + (long long)tid*4; i < hi; i += 256*4) {
        float4 v;
        if (i + 3 < hi) v = *reinterpret_cast<const float4*>(p + i);
        else {
            v = make_float4(0.f,0.f,0.f,0.f);
            v.x = p[i];
            if (i+1 < hi) v.y = p[i+1];
            if (i+2 < hi) v.z = p[i+2];
        }
        const float xsv[4] = {v.x, v.y, v.z, v.w};
#pragma unroll
        for (int j = 0; j < 4; ++j) {
            const float x = xsv[j];
            const float xv = ISQT ? __fmul_rn(x, x) : fabsf(x);
#pragma unroll
            for (int s = 0; s < NSLOT; ++s)
                acc[s] += (int)rintf(xv * scale[s]);   // xv*2^k exact; RTE int
        }
    }

    __shared__ double lred[4][NSLOT];
    const int lane = tid & 63, wv = tid >> 6;
#pragma unroll
    for (int s = 0; s < NSLOT; ++s) {
        double r = wred64((double)acc[s]);
        if (lane == 0) lred[wv][s] = r;
    }
    __syncthreads();
    if (tid < NSLOT)
        krow[(long long)tid * ntg + tile] =
            lred[0][tid]+lred[1][tid]+lred[2][tid]+lred[3][tid];
}

__global__ __launch_bounds__(256) void passA7(const float* __restrict__ streams,
        const int* __restrict__ hdr, const double* __restrict__ A0d,
        double* __restrict__ Ktab, long long ntg)
{
    const int ch = blockIdx.y;
    const int STR[NCH] = {0,1,3,0,1,2,3};
    const int st = STR[ch];
    const long long cnt = (long long)hdr[st];
    const long long tile = blockIdx.x;
    if (tile * TS >= cnt) return;
    const int em = emin_of(A0d[ch]);
    const float base = (em == 12345) ? 0.0f : ldexpf(1.0f, 23 - em);
    const float* p = streams + hdr[4+st];
    double* krow = Ktab + (long long)ch * NSLOT * ntg;
    if (ch < 3) passA_one<0>(p, cnt, krow, ntg, tile, base);
    else        passA_one<1>(p, cnt, krow, ntg, tile, base);
}

// ---------------- walk: windowed binade walk (proven semantics) ----------------
__global__ __launch_bounds__(64) void walk2(const float* __restrict__ streams,
        const int* __restrict__ hdr, const double* __restrict__ A0d,
        const double* __restrict__ Ktab, float* __restrict__ chains, long long ntg)
{
    const int ch = blockIdx.x;
    const int lane = threadIdx.x;
    const int STR[NCH]  = {0,1,3,0,1,2,3};
    const int ISQ[NCH]  = {0,0,0,1,1,1,1};
    const int OSLOT[NCH]= {0,1,3,4,5,6,7};
    const int st = STR[ch], isq = ISQ[ch];
    const long long cnt = (long long)hdr[st];
    const float* p = streams + hdr[4+st];
    const long long ntiles = (cnt + TS - 1) / TS;
    const double* krow = Ktab + (long long)ch * NSLOT * ntg;
    const int em = emin_of(A0d[ch]);

    double A = A0d[ch];
    long long t = 1;
    while (t < ntiles) {
        if (A > 0.0 && em != 12345) {
            const int e = expo_bits(A);
            const int slot = e - em;
            if (slot >= 0 && slot < NSLOT) {
                const long long wt = t + lane;
                double Kv = (wt < ntiles) ? krow[(long long)slot * ntg + wt] : 0.0;
                double P = Kv;
#pragma unroll
                for (int d = 1; d < 64; d <<= 1) {
                    double tt = __shfl_up(P, d, 64);
                    if (lane >= d) P += tt;
                }
                const double u  = ldexp(1.0, e - 23);
                const double Bb = ldexp(1.0, e + 1);
                const bool bad = (A + u * P > Bb);
                const unsigned long long bal = __ballot(bad);
                if (bal == 0ULL) { A += u * __shfl(P, 63); t += 64; continue; }
                const int F = __ffsll((long long)bal) - 1;
                if (F > 0) { A += u * __shfl(P, F - 1); t += F; }
                const long long lo = t * (long long)TS;
                long long hi = lo + TS; if (hi > cnt) hi = cnt;
                span_st(p, isq, A, lo, hi, lane);
                ++t;
                continue;
            }
        }
        const long long lo = t * (long long)TS;
        long long hi = lo + TS; if (hi > cnt) hi = cnt;
        span_st(p, isq, A, lo, hi, lane);
        ++t;
    }
    if (lane == 0) chains[OSLOT[ch]] = (float)A;
}

// ---------------- finalize (proven R9) ----------------
__global__ void fin2(const float* __restrict__ chains,
                     const double* __restrict__ diag,
                     const int* __restrict__ hdr,
                     const float* __restrict__ alpha,
                     float* __restrict__ out, long long n)
{
    const float a = alpha[0];
    const float s_np[4]  = { -chains[0], -chains[1], (float)diag[2], chains[3] };
    const float sq_np[4] = {  chains[4],  chains[5],  chains[6],     chains[7] };
    float tmse = 0.f, tvar = 0.f;
#pragma unroll
    for (int b = 0; b < 4; ++b) {
        float cnt = fminf((float)hdr[b], 16777216.0f);
        float safe = fmaxf(cnt, 1.0f);
        float mean = __fdiv_rn(s_np[b], safe);
        float var  = __fsub_rn(__fdiv_rn(sq_np[b], safe), __fmul_rn(mean, mean));
        float lvl  = __fmul_rn((float)(b - 2), a);
        float e    = __fsub_rn(mean, lvl);
        if (cnt > 0.f)  tmse = __fadd_rn(tmse, __fmul_rn(e, e));
        if (cnt >= 2.f) tvar = __fadd_rn(tvar, var);
    }
    out[0] = __fadd_rn(tmse, tvar);
    out[1] = tmse;
    out[2] = tvar;
    out[3] = (float)(diag[1] / (double)n);
    out[4] = (float)(diag[0] / (double)n);
}

// ================= TIER 3: R6 bit-exact serial fallback =================
__global__ __launch_bounds__(64) void zero_diag6(double* __restrict__ diag) {
    if (threadIdx.x < 6) diag[threadIdx.x] = 0.0;
}
__global__ __launch_bounds__(256) void diag6(const float* __restrict__ w,
        const float* __restrict__ alpha, double* __restrict__ diag, int n4, long long n)
{
    const float a = alpha[0];
    float ad = 0.f, dd = 0.f; int c0=0,c1=0,c2=0,c3=0;
    auto pe = [&](float x) {
        float r = __fdiv_rn(x, a);
        float cl = fminf(1.0f, fmaxf(-2.0f, r));
        float bf = rintf(cl); int k = (int)bf;
        float wq = __fmul_rn(bf, a); float d = __fsub_rn(x, wq);
        ad = __fadd_rn(ad, fabsf(d)); dd = __fadd_rn(dd, __fmul_rn(d, d));
        if (k==-2) c0++; else if (k==-1) c1++; else if (k==0) c2++; else c3++;
    };
    const float4* w4 = reinterpret_cast<const float4*>(w);
    const int stride = gridDim.x * 256;
    for (int i = blockIdx.x * 256 + threadIdx.x; i < n4; i += stride) {
        float4 v = w4[i]; pe(v.x); pe(v.y); pe(v.z); pe(v.w);
    }
    if (blockIdx.x == 0 && threadIdx.x == 0)
        for (long long i = (long long)n4 * 4; i < n; ++i) pe(w[i]);
    double vals[6] = {(double)ad,(double)dd,(double)c0,(double)c1,(double)c2,(double)c3};
    __shared__ double red[256];
    const int tid = threadIdx.x;
#pragma unroll
    for (int j = 0; j < 6; ++j) {
        red[tid] = vals[j]; __syncthreads();
        for (int s = 128; s > 0; s >>= 1) { if (tid < s) red[tid] += red[tid+s]; __syncthreads(); }
        if (tid == 0) atomicAdd(&diag[j], red[0]);
        __syncthreads();
    }
}
__global__ __launch_bounds__(64) void seq_chains(const float* __restrict__ w,
        const float* __restrict__ alpha, float* __restrict__ chains, long long n)
{
    const float a = alpha[0];
    const int lane = threadIdx.x; const int myrow = lane & 7;
    __shared__ float val[8][64];
    float acc = 0.0f;
    const long long ntl = (n + 63) / 64;
    float x_next = (lane < n) ? w[lane] : 0.0f;
    for (long long t = 0; t < ntl; ++t) {
        float x = x_next;
        { long long idxn = (t + 1) * 64 + lane; x_next = (idxn < n) ? w[idxn] : 0.0f; }
        const long long idx = t * 64 + lane;
        const bool valid = (idx < n);
        float r = __fdiv_rn(x, a);
        float cl = fminf(1.0f, fmaxf(-2.0f, r));
        int k = (int)rintf(cl); int row = k + 2;
        float xx = __fmul_rn(x, x);
#pragma unroll
        for (int b = 0; b < 4; ++b) {
            val[b][lane]     = (valid && row == b) ? x  : 0.0f;
            val[4 + b][lane] = (valid && row == b) ? xx : 0.0f;
        }
        __syncthreads();
        if (lane < 8) {
#pragma unroll
            for (int e4i = 0; e4i < 16; ++e4i) {
                float4 v = *reinterpret_cast<const float4*>(&val[myrow][e4i * 4]);
                acc = __fadd_rn(acc, v.x); acc = __fadd_rn(acc, v.y);
                acc = __fadd_rn(acc, v.z); acc = __fadd_rn(acc, v.w);
            }
        }
        __syncthreads();
    }
    if (lane < 8) chains[lane] = acc;
}
__global__ void fin_seq(const float* __restrict__ chains, const double* __restrict__ diag,
                        const float* __restrict__ alpha, float* __restrict__ out, long long n)
{
    const float a = alpha[0];
    float tmse = 0.0f, tvar = 0.0f;
#pragma unroll
    for (int b = 0; b < 4; ++b) {
        float cnt = fminf((float)diag[2 + b], 16777216.0f);
        float safe = fmaxf(cnt, 1.0f);
        float mean = __fdiv_rn(chains[b], safe);
        float var  = __fsub_rn(__fdiv_rn(chains[4 + b], safe), __fmul_rn(mean, mean));
        float lvl  = __fmul_rn((float)(b - 2), a);
        float e    = __fsub_rn(mean, lvl);
        if (cnt > 0.0f)  tmse = __fadd_rn(tmse, __fmul_rn(e, e));
        if (cnt >= 2.0f) tvar = __fadd_rn(tvar, var);
    }
    out[0] = __fadd_rn(tmse, tvar);
    out[1] = tmse; out[2] = tvar;
    out[3] = (float)(diag[1] / (double)n);
    out[4] = (float)(diag[0] / (double)n);
}

// ---------------- launcher ----------------
extern "C" void kernel_launch(void* const* d_in, const int* in_sizes, int n_in,
                              void* d_out, int out_size, void* d_ws, size_t ws_size,
                              hipStream_t stream) {
    const float* w     = (const float*)d_in[0];
    const float* alpha = (const float*)d_in[1];
    float* out = (float*)d_out;
    const long long n = (long long)in_sizes[0];
    const long long ntg = (n + TS - 1) / TS;

    size_t off = 0;
    const size_t ktab_off = off;   off += (size_t)NCH * NSLOT * ntg * 8;
    const size_t hist_off = off;   off += (size_t)NPART * 4 * 4;
    const size_t bbase_off = off;  off += (size_t)NPART * 4 * 4;
    const size_t hdr_off = off;    off += 8 * 4;
    const size_t diag_off = (off + 7) & ~(size_t)7;  off = diag_off + 8 * 8;
    const size_t a0_off = off;     off += 8 * 8;
    const size_t chains_off = off; off += 8 * 4;
    const size_t streams_off = (off + 255) & ~(size_t)255;
    const size_t need1 = streams_off + ((size_t)n + 512) * 4;

    if (ws_size >= need1) {
        double* Ktab   = (double*)((char*)d_ws + ktab_off);
        int*    hist   = (int*)   ((char*)d_ws + hist_off);
        int*    bbase  = (int*)   ((char*)d_ws + bbase_off);
        int*    hdr    = (int*)   ((char*)d_ws + hdr_off);
        double* diag   = (double*)((char*)d_ws + diag_off);
        double* A0d    = (double*)((char*)d_ws + a0_off);
        float*  chains = (float*) ((char*)d_ws + chains_off);
        float*  strm   = (float*) ((char*)d_ws + streams_off);
        long long nseg = ((n + NPART - 1) / NPART + 1023) & ~1023LL;

        zero2<<<1, 64, 0, stream>>>(diag, chains, A0d);
        part1<<<NPART, PBT, 0, stream>>>(w, alpha, hist, diag, n, nseg);
        scank<<<1, 256, 0, stream>>>(hist, bbase, hdr);
        part2<<<NPART, PBT, 0, stream>>>(w, alpha, bbase, hdr, strm, n, nseg);
        span0<<<NCH, 64, 0, stream>>>(strm, hdr, A0d);
        dim3 ga((unsigned)ntg, NCH);
        passA7<<<ga, 256, 0, stream>>>(strm, hdr, A0d, Ktab, ntg);
        walk2<<<NCH, 64, 0, stream>>>(strm, hdr, A0d, Ktab, chains, ntg);
        fin2<<<1, 1, 0, stream>>>(chains, diag, hdr, alpha, out, n);
    } else {
        float*  chains = (float*)d_ws;
        double* diag   = (double*)((char*)d_ws + 128);
        zero_diag6<<<1, 64, 0, stream>>>(diag);
        diag6<<<1024, 256, 0, stream>>>(w, alpha, diag, (int)(n >> 2), n);
        seq_chains<<<1, 64, 0, stream>>>(w, alpha, chains, n);
        fin_seq<<<1, 1, 0, stream>>>(chains, diag, alpha, out, n);
    }
}